// Round 7
// baseline (478.911 us; speedup 1.0000x reference)
//
#include <hip/hip_runtime.h>
#include <math.h>

#define LL 8192
#define CC 96
#define DINc 96
#define NN 16
#define RR 6
#define KK 8
#define Dd 16
#define Hh 16
#define Ww 32
#define NCH 32
#define CHL 256   // LL / NCH

__constant__ int Pc_[4][3] = {{0,1,2},{1,2,0},{2,0,1},{2,1,0}};

__device__ __forceinline__ float silu_(float x){ return x / (1.f + __expf(-x)); }

// ---------------- K1: LN over C at each l -> xn CHANNEL-MAJOR [c][l] ----------------
__global__ void k_ln1(const float* __restrict__ inp, const float* __restrict__ w,
                      const float* __restrict__ b, float* __restrict__ xn_cm) {
    int l = blockIdx.x * blockDim.x + threadIdx.x;
    if (l >= LL) return;
    const float* p = inp + l * CC;
    float m = 0.f;
    for (int c = 0; c < CC; ++c) m += p[c];
    m *= (1.f / CC);
    float v = 0.f;
    for (int c = 0; c < CC; ++c) { float d = p[c] - m; v += d * d; }
    v *= (1.f / CC);
    float r = rsqrtf(v + 1e-6f);
    for (int c = 0; c < CC; ++c) xn_cm[c * LL + l] = (p[c] - m) * r * w[c] + b[c];
}

// ---------------- KW: transpose weights (in_proj, x_proj, cab convs) ----------------
__global__ void k_wtrans(const float* __restrict__ inpj, const float* __restrict__ xpw,
                         const float* __restrict__ w1, const float* __restrict__ w2,
                         float* __restrict__ ipT, float* __restrict__ xpT,
                         float* __restrict__ wT1, float* __restrict__ wT2) {
    int idx = blockIdx.x * blockDim.x + threadIdx.x;
    if (idx < 82944) {   // wT1: [ic][tap][oc=32]
        int oc = idx & 31; int tap = (idx >> 5) % 27; int ic = idx / (32 * 27);
        wT1[idx] = w1[(oc * 96 + ic) * 27 + tap];
    }
    if (idx < 82944) {   // wT2: [ic][tap][oc=96]
        int oc = idx % 96; int tap = (idx / 96) % 27; int ic = idx / (96 * 27);
        wT2[idx] = w2[(oc * 32 + ic) * 27 + tap];
    }
    if (idx < 18432) {   // ipT: [c][e=192]
        int e = idx % 192; int c = idx / 192;
        ipT[idx] = inpj[e * 96 + c];
    }
    if (idx < 29184) {   // xpT: [k][c][e=38]
        int e = idx % 38; int c = (idx / 38) % 96; int k = idx / (38 * 96);
        xpT[idx] = xpw[(k * 38 + e) * 96 + c];
    }
}

// ---------------- K2: in_proj, 8-e register block, uniform weights ----------------
__global__ void k_inproj(const float* __restrict__ xn_cm, const float* __restrict__ ipT,
                         float* __restrict__ xcm, float* __restrict__ z_cm) {
    int bx = blockIdx.x;
    int eb = bx >> 5;                       // 0..23 (uniform)
    int l  = ((bx & 31) << 8) + threadIdx.x;
    int e0 = eb << 3;
    float a[8];
    #pragma unroll
    for (int j = 0; j < 8; ++j) a[j] = 0.f;
    const float* wp = ipT + e0;
    for (int c = 0; c < CC; ++c) {
        float x = xn_cm[c * LL + l];
        const float4* wv = (const float4*)(wp + c * 192);
        float4 wa = wv[0], wb = wv[1];
        a[0] += x * wa.x; a[1] += x * wa.y; a[2] += x * wa.z; a[3] += x * wa.w;
        a[4] += x * wb.x; a[5] += x * wb.y; a[6] += x * wb.z; a[7] += x * wb.w;
    }
    float* dst = (e0 < DINc) ? (xcm + (long)e0 * LL) : (z_cm + (long)(e0 - DINc) * LL);
    #pragma unroll
    for (int j = 0; j < 8; ++j) dst[(long)j * LL + l] = a[j];
}

// ---------------- K3: depthwise conv3d + SiLU -> xs[0] ----------------
__global__ void k_dwconv(const float* __restrict__ xcm, const float* __restrict__ cw,
                         const float* __restrict__ cb, float* __restrict__ xs0) {
    int idx = blockIdx.x * blockDim.x + threadIdx.x;
    if (idx >= DINc * LL) return;
    int l = idx & (LL - 1);
    int c = idx >> 13;
    int w = l & (Ww - 1);
    int h = (l >> 5) & (Hh - 1);
    int d = l >> 9;
    float s = cb[c];
    const float* xp = xcm + c * LL;
    const float* wp = cw + c * 27;
    for (int kd = -1; kd <= 1; ++kd) {
        int dd = d + kd; if ((unsigned)dd >= Dd) continue;
        for (int kh = -1; kh <= 1; ++kh) {
            int hh = h + kh; if ((unsigned)hh >= Hh) continue;
            for (int kw = -1; kw <= 1; ++kw) {
                int ww2 = w + kw; if ((unsigned)ww2 >= Ww) continue;
                s += xp[(dd * Hh + hh) * Ww + ww2] * wp[(kd + 1) * 9 + (kh + 1) * 3 + (kw + 1)];
            }
        }
    }
    xs0[c * LL + l] = silu_(s);
}

// ---------------- K4: build xs[1..7] ----------------
__global__ void k_perm(float* __restrict__ xs) {
    int idx = blockIdx.x * blockDim.x + threadIdx.x;
    if (idx >= 7 * DINc * LL) return;
    int l = idx & (LL - 1);
    int c = (idx >> 13) % DINc;
    int k = idx / (DINc * LL) + 1;
    int i  = (k < 4) ? k : (k - 4);
    int lp = (k < 4) ? l : (LL - 1 - l);
    int p0 = Pc_[i][0], p1 = Pc_[i][1], p2 = Pc_[i][2];
    const int sp[3] = {Dd, Hh, Ww};
    int pd1 = sp[p1], pd2 = sp[p2];
    int i2 = lp % pd2;
    int t  = lp / pd2;
    int i1 = t % pd1;
    int i0 = t / pd1;
    int coord[3];
    coord[p0] = i0; coord[p1] = i1; coord[p2] = i2;
    int o = (coord[0] * Hh + coord[1]) * Ww + coord[2];
    xs[(k * DINc + c) * LL + l] = xs[c * LL + o];
}

// ---------------- K5: x_dbl, 38 accumulators per (k,l), xs read once ----------------
__global__ void k_xdbl(const float* __restrict__ xs, const float* __restrict__ xpT,
                       float* __restrict__ dtraw, float* __restrict__ Bb, float* __restrict__ Cb) {
    int bx = blockIdx.x;
    int k = bx >> 5;                        // uniform
    int l = ((bx & 31) << 8) + threadIdx.x;
    float acc[38];
    #pragma unroll
    for (int e = 0; e < 38; ++e) acc[e] = 0.f;
    const float* xb = xs + (long)k * DINc * LL + l;
    const float* wb = xpT + k * DINc * 38;
    for (int c = 0; c < DINc; ++c) {
        float x = xb[(long)c * LL];
        const float* wr = wb + c * 38;
        #pragma unroll
        for (int e = 0; e < 38; ++e) acc[e] += x * wr[e];
    }
    #pragma unroll
    for (int r = 0; r < RR; ++r) dtraw[(k * RR + r) * LL + l] = acc[r];
    float* Bp = Bb + ((long)k * LL + l) * NN;
    float* Cp = Cb + ((long)k * LL + l) * NN;
    #pragma unroll
    for (int n = 0; n < NN; ++n) { Bp[n] = acc[RR + n]; Cp[n] = acc[RR + NN + n]; }
}

// ---------------- softplus ----------------
__device__ __forceinline__ float softplus_(float x) {
    return (x > 20.f) ? x : __logf(1.f + __expf(x));
}

// ---------------- K7a: chunk-local scan -> (Aprod, Bacc); LDS (dt,du) pair broadcast ----------------
__global__ void k_scan1(const float* __restrict__ xs, const float* __restrict__ dtraw,
                        const float* __restrict__ Bb, const float* __restrict__ A_logs,
                        const float* __restrict__ dt_w, const float* __restrict__ dt_b,
                        float* __restrict__ Ap, float* __restrict__ Bc) {
    __shared__ float2 sdu[256];
    int t = blockIdx.x * blockDim.x + threadIdx.x;
    int n = t & 15;
    int gc = t >> 4;
    if (gc >= KK * DINc * NCH) return;
    int gbase = threadIdx.x & ~15;
    int grp = gc >> 5;
    int chunk = gc & (NCH - 1);
    int k = grp / DINc;
    float A_n = -__expf(A_logs[grp * NN + n]);
    float w0 = dt_w[grp * RR + 0], w1 = dt_w[grp * RR + 1], w2 = dt_w[grp * RR + 2];
    float w3 = dt_w[grp * RR + 3], w4 = dt_w[grp * RR + 4], w5 = dt_w[grp * RR + 5];
    float dtb = dt_b[grp];
    const float* drb  = dtraw + (long)k * RR * LL + chunk * CHL;
    const float* urow = xs + (long)grp * LL + chunk * CHL;
    const float* Bblk = Bb + ((long)k * LL + chunk * CHL) * NN + n;
    float hc = 0.f, dsuml = 0.f;
    for (int base = 0; base < CHL; base += 16) {
        int lm = base + n;
        float dtl = dtb + drb[lm] * w0 + drb[LL + lm] * w1 + drb[2 * LL + lm] * w2
                        + drb[3 * LL + lm] * w3 + drb[4 * LL + lm] * w4 + drb[5 * LL + lm] * w5;
        float dt_lane = softplus_(dtl);
        float u_lane  = urow[lm];
        sdu[threadIdx.x] = make_float2(dt_lane, dt_lane * u_lane);
        dsuml += dt_lane;
        #pragma unroll
        for (int j = 0; j < 16; ++j) {
            float2 v = sdu[gbase + j];
            float a  = __expf(v.x * A_n);
            hc = a * hc + v.y * Bblk[(base + j) * NN];
        }
    }
    dsuml += __shfl_xor(dsuml, 1, 16);
    dsuml += __shfl_xor(dsuml, 2, 16);
    dsuml += __shfl_xor(dsuml, 4, 16);
    dsuml += __shfl_xor(dsuml, 8, 16);
    int o = (grp * NN + n) * NCH + chunk;
    Ap[o] = __expf(A_n * dsuml);
    Bc[o] = hc;
}

// ---------------- K7b: combine chunk transfers ----------------
__global__ void k_scan2(const float* __restrict__ Ap, const float* __restrict__ Bc,
                        float* __restrict__ hs) {
    int t = blockIdx.x * blockDim.x + threadIdx.x;
    if (t >= KK * DINc * NN) return;
    int base = t * NCH;
    float h = 0.f;
    for (int c = 0; c < NCH; ++c) {
        hs[base + c] = h;
        h = Ap[base + c] * h + Bc[base + c];
    }
}

// ---------------- K7c: final scan; LDS pair broadcast + deferred 4-stage tree reduce ----------------
__global__ void k_scan3(float* __restrict__ xs_ys, const float* __restrict__ dtraw,
                        const float* __restrict__ Bb, const float* __restrict__ Cb,
                        const float* __restrict__ A_logs, const float* __restrict__ dt_w,
                        const float* __restrict__ dt_b, const float* __restrict__ Ds,
                        const float* __restrict__ hs) {
    __shared__ float2 sdu[256];
    int t = blockIdx.x * blockDim.x + threadIdx.x;
    int n = t & 15;
    int gc = t >> 4;
    if (gc >= KK * DINc * NCH) return;
    int gbase = threadIdx.x & ~15;
    int grp = gc >> 5;
    int chunk = gc & (NCH - 1);
    int k = grp / DINc;
    float A_n = -__expf(A_logs[grp * NN + n]);
    float w0 = dt_w[grp * RR + 0], w1 = dt_w[grp * RR + 1], w2 = dt_w[grp * RR + 2];
    float w3 = dt_w[grp * RR + 3], w4 = dt_w[grp * RR + 4], w5 = dt_w[grp * RR + 5];
    float dtb = dt_b[grp];
    float Dv  = Ds[grp];
    const float* drb  = dtraw + (long)k * RR * LL + chunk * CHL;
    const float* Bblk = Bb + ((long)k * LL + chunk * CHL) * NN + n;
    const float* Cblk = Cb + ((long)k * LL + chunk * CHL) * NN + n;
    float* urow = xs_ys + (long)grp * LL + chunk * CHL;
    float hc = hs[(grp * NN + n) * NCH + chunk];
    bool b0 = (n & 1), b1 = ((n >> 1) & 1), b2 = ((n >> 2) & 1), b3 = (n >> 3);
    for (int base = 0; base < CHL; base += 16) {
        int lm = base + n;
        float dtl = dtb + drb[lm] * w0 + drb[LL + lm] * w1 + drb[2 * LL + lm] * w2
                        + drb[3 * LL + lm] * w3 + drb[4 * LL + lm] * w4 + drb[5 * LL + lm] * w5;
        float dt_lane = softplus_(dtl);
        float u_lane  = urow[lm];
        sdu[threadIdx.x] = make_float2(dt_lane, dt_lane * u_lane);
        float p[16];
        #pragma unroll
        for (int j = 0; j < 16; ++j) {
            float2 v = sdu[gbase + j];
            float a  = __expf(v.x * A_n);
            hc = a * hc + v.y * Bblk[(base + j) * NN];
            p[j] = hc * Cblk[(base + j) * NN];
        }
        float q[8];
        #pragma unroll
        for (int m = 0; m < 8; ++m) {
            float s = b0 ? p[2*m] : p[2*m+1];
            float r = __shfl_xor(s, 1, 16);
            q[m] = (b0 ? p[2*m+1] : p[2*m]) + r;
        }
        float r4[4];
        #pragma unroll
        for (int m = 0; m < 4; ++m) {
            float s = b1 ? q[2*m] : q[2*m+1];
            float r = __shfl_xor(s, 2, 16);
            r4[m] = (b1 ? q[2*m+1] : q[2*m]) + r;
        }
        float t2r[2];
        #pragma unroll
        for (int m = 0; m < 2; ++m) {
            float s = b2 ? r4[2*m] : r4[2*m+1];
            float r = __shfl_xor(s, 4, 16);
            t2r[m] = (b2 ? r4[2*m+1] : r4[2*m]) + r;
        }
        float s = b3 ? t2r[0] : t2r[1];
        float r = __shfl_xor(s, 8, 16);
        float yv = (b3 ? t2r[1] : t2r[0]) + r;
        urow[base + n] = yv + Dv * u_lane;
    }
}

// ---------------- K8: inverse-permute + sum 8 directions ----------------
__global__ void k_combine(const float* __restrict__ ys, float* __restrict__ acc) {
    int idx = blockIdx.x * blockDim.x + threadIdx.x;
    if (idx >= LL * DINc) return;
    int c = idx % DINc;
    int l = idx / DINc;
    int w = l & (Ww - 1);
    int h = (l >> 5) & (Hh - 1);
    int d = l >> 9;
    int coord[3] = {d, h, w};
    const int sp[3] = {Dd, Hh, Ww};
    float s = 0.f;
    #pragma unroll
    for (int i = 0; i < 4; ++i) {
        int p0 = Pc_[i][0], p1 = Pc_[i][1], p2 = Pc_[i][2];
        int lp = (coord[p0] * sp[p1] + coord[p1]) * sp[p2] + coord[p2];
        s += ys[(long)(i * DINc + c) * LL + lp];
        s += ys[(long)((4 + i) * DINc + c) * LL + (LL - 1 - lp)];
    }
    acc[l * DINc + c] = s;
}

// ---------------- K9: out_norm LN * silu(z_cm) ----------------
__global__ void k_outnorm(const float* __restrict__ acc, const float* __restrict__ z_cm,
                          const float* __restrict__ w, const float* __restrict__ b,
                          float* __restrict__ y) {
    int l = blockIdx.x * blockDim.x + threadIdx.x;
    if (l >= LL) return;
    const float* a = acc + l * DINc;
    float m = 0.f;
    for (int c = 0; c < DINc; ++c) m += a[c];
    m *= (1.f / DINc);
    float v = 0.f;
    for (int c = 0; c < DINc; ++c) { float d = a[c] - m; v += d * d; }
    v *= (1.f / DINc);
    float r = rsqrtf(v + 1e-5f);
    for (int c = 0; c < DINc; ++c) {
        float zz = z_cm[(long)c * LL + l];
        y[l * DINc + c] = ((a[c] - m) * r * w[c] + b[c]) * silu_(zz);
    }
}

// ---------------- K10: out_proj + skip1 ----------------
__global__ void k_outproj(const float* __restrict__ y, const float* __restrict__ opw,
                          const float* __restrict__ inp, const float* __restrict__ skip1,
                          float* __restrict__ xafter) {
    int idx = blockIdx.x * blockDim.x + threadIdx.x;
    if (idx >= LL * CC) return;
    int c = idx % CC;
    int l = idx / CC;
    const float* yr = y + l * DINc;
    const float* wr = opw + c * DINc;
    float s = 0.f;
    for (int e = 0; e < DINc; ++e) s += yr[e] * wr[e];
    xafter[l * CC + c] = inp[l * CC + c] * skip1[c] + s;
}

// ---------------- K11: LN2 -> channel-major ----------------
__global__ void k_ln2(const float* __restrict__ xafter, const float* __restrict__ w,
                      const float* __restrict__ b, float* __restrict__ y2) {
    int l = blockIdx.x * blockDim.x + threadIdx.x;
    if (l >= LL) return;
    const float* p = xafter + l * CC;
    float m = 0.f;
    for (int c = 0; c < CC; ++c) m += p[c];
    m *= (1.f / CC);
    float v = 0.f;
    for (int c = 0; c < CC; ++c) { float d = p[c] - m; v += d * d; }
    v *= (1.f / CC);
    float r = rsqrtf(v + 1e-5f);
    for (int c = 0; c < CC; ++c) y2[c * LL + l] = (p[c] - m) * r * w[c] + b[c];
}

// ---------------- K12: conv3d 96->32, 8-way ic-split, batched 27-load ILP ----------------
__global__ void k_conv1(const float* __restrict__ y2, const float* __restrict__ wT,
                        float* __restrict__ part) {
    int bx = blockIdx.x;
    int g = bx >> 5;
    int l = ((bx & 31) << 8) + threadIdx.x;
    int ocg = g & 3;
    int isp = g >> 2;
    int w = l & (Ww - 1);
    int h = (l >> 5) & (Hh - 1);
    int d = l >> 9;
    int off[27];
    float msk[27];
    #pragma unroll
    for (int kd = 0; kd < 3; ++kd) {
        #pragma unroll
        for (int kh = 0; kh < 3; ++kh) {
            #pragma unroll
            for (int kw = 0; kw < 3; ++kw) {
                int dd = d + kd - 1, hh = h + kh - 1, ww2 = w + kw - 1;
                bool v = ((unsigned)dd < Dd) & ((unsigned)hh < Hh) & ((unsigned)ww2 < Ww);
                int dc = v ? dd : 0, hc = v ? hh : 0, wc = v ? ww2 : 0;
                off[kd * 9 + kh * 3 + kw] = (dc * Hh + hc) * Ww + wc;
                msk[kd * 9 + kh * 3 + kw] = v ? 1.f : 0.f;
            }
        }
    }
    float a[8];
    #pragma unroll
    for (int j = 0; j < 8; ++j) a[j] = 0.f;
    for (int ic = isp * 12; ic < isp * 12 + 12; ++ic) {
        const float* xp = y2 + (long)ic * LL;
        float xv[27];
        #pragma unroll
        for (int t = 0; t < 27; ++t) xv[t] = xp[off[t]];
        const float* wb = wT + ic * 27 * 32 + ocg * 8;
        #pragma unroll
        for (int t = 0; t < 27; ++t) {
            float x = xv[t] * msk[t];
            const float4* wv = (const float4*)(wb + t * 32);
            float4 wa = wv[0], wbv = wv[1];
            a[0] += x * wa.x;  a[1] += x * wa.y;  a[2] += x * wa.z;  a[3] += x * wa.w;
            a[4] += x * wbv.x; a[5] += x * wbv.y; a[6] += x * wbv.z; a[7] += x * wbv.w;
        }
    }
    float* pp = part + ((long)(isp * 32 + ocg * 8)) * LL + l;
    #pragma unroll
    for (int j = 0; j < 8; ++j) pp[(long)j * LL] = a[j];
}

// ---------------- K12b: t1 = GELU(sum 8 partials + bias) ----------------
__global__ void k_gelusum(const float* __restrict__ part, const float* __restrict__ b1,
                          float* __restrict__ t1) {
    int idx = blockIdx.x * blockDim.x + threadIdx.x;
    if (idx >= 32 * LL) return;
    int l = idx & (LL - 1);
    int oc = idx >> 13;
    float s = b1[oc];
    #pragma unroll
    for (int isp = 0; isp < 8; ++isp)
        s += part[((long)(isp * 32 + oc)) * LL + l];
    t1[oc * LL + l] = 0.5f * s * (1.f + erff(s * 0.70710678118654752f));
}

// ---------------- K13: conv3d 32->96, 4-way ic-split, batched 27-load ILP ----------------
__global__ void k_conv2(const float* __restrict__ t1, const float* __restrict__ wT,
                        float* __restrict__ part) {
    int bx = blockIdx.x;
    int g = bx >> 5;
    int l = ((bx & 31) << 8) + threadIdx.x;
    int ocg = g % 12;
    int isp = g / 12;
    int w = l & (Ww - 1);
    int h = (l >> 5) & (Hh - 1);
    int d = l >> 9;
    int off[27];
    float msk[27];
    #pragma unroll
    for (int kd = 0; kd < 3; ++kd) {
        #pragma unroll
        for (int kh = 0; kh < 3; ++kh) {
            #pragma unroll
            for (int kw = 0; kw < 3; ++kw) {
                int dd = d + kd - 1, hh = h + kh - 1, ww2 = w + kw - 1;
                bool v = ((unsigned)dd < Dd) & ((unsigned)hh < Hh) & ((unsigned)ww2 < Ww);
                int dc = v ? dd : 0, hc = v ? hh : 0, wc = v ? ww2 : 0;
                off[kd * 9 + kh * 3 + kw] = (dc * Hh + hc) * Ww + wc;
                msk[kd * 9 + kh * 3 + kw] = v ? 1.f : 0.f;
            }
        }
    }
    float a[8];
    #pragma unroll
    for (int j = 0; j < 8; ++j) a[j] = 0.f;
    for (int ic = isp * 8; ic < isp * 8 + 8; ++ic) {
        const float* xp = t1 + (long)ic * LL;
        float xv[27];
        #pragma unroll
        for (int t = 0; t < 27; ++t) xv[t] = xp[off[t]];
        const float* wb = wT + ic * 27 * 96 + ocg * 8;
        #pragma unroll
        for (int t = 0; t < 27; ++t) {
            float x = xv[t] * msk[t];
            const float4* wv = (const float4*)(wb + t * 96);
            float4 wa = wv[0], wbv = wv[1];
            a[0] += x * wa.x;  a[1] += x * wa.y;  a[2] += x * wa.z;  a[3] += x * wa.w;
            a[4] += x * wbv.x; a[5] += x * wbv.y; a[6] += x * wbv.z; a[7] += x * wbv.w;
        }
    }
    float* pp = part + ((long)(isp * 96 + ocg * 8)) * LL + l;
    #pragma unroll
    for (int j = 0; j < 8; ++j) pp[(long)j * LL] = a[j];
}

// ---------------- K13b: t2 = sum 4 partials + bias ----------------
__global__ void k_conv2sum(const float* __restrict__ part, const float* __restrict__ b2,
                           float* __restrict__ t2) {
    int idx = blockIdx.x * blockDim.x + threadIdx.x;
    if (idx >= 96 * LL) return;
    int l = idx & (LL - 1);
    int oc = idx >> 13;
    float s = b2[oc];
    #pragma unroll
    for (int isp = 0; isp < 4; ++isp)
        s += part[((long)(isp * 96 + oc)) * LL + l];
    t2[oc * LL + l] = s;
}

// ---------------- K14a: per-channel mean ----------------
__global__ void k_mean(const float* __restrict__ t2, float* __restrict__ mbuf) {
    __shared__ float sm[256];
    int c = blockIdx.x;
    float a = 0.f;
    for (int l = threadIdx.x; l < LL; l += 256) a += t2[c * LL + l];
    sm[threadIdx.x] = a;
    __syncthreads();
    for (int o = 128; o > 0; o >>= 1) {
        if (threadIdx.x < o) sm[threadIdx.x] += sm[threadIdx.x + o];
        __syncthreads();
    }
    if (threadIdx.x == 0) mbuf[c] = sm[0] * (1.f / LL);
}

// ---------------- K14b: channel-attention MLP ----------------
__global__ void k_mlp(const float* __restrict__ mbuf, const float* __restrict__ w1,
                      const float* __restrict__ b1, const float* __restrict__ w2,
                      const float* __restrict__ b2, float* __restrict__ v2) {
    __shared__ float v[48];
    int t = threadIdx.x;
    if (t < 48) {
        float s = b1[t];
        for (int c = 0; c < 96; ++c) s += mbuf[c] * w1[t * 96 + c];
        v[t] = fmaxf(s, 0.f);
    }
    __syncthreads();
    if (t < 96) {
        float s = b2[t];
        for (int j = 0; j < 48; ++j) s += v[j] * w2[t * 48 + j];
        v2[t] = 1.f / (1.f + __expf(-s));
    }
}

// ---------------- K15: final residual ----------------
__global__ void k_final(const float* __restrict__ xafter, const float* __restrict__ skip2,
                        const float* __restrict__ t2, const float* __restrict__ v2,
                        float* __restrict__ out) {
    int idx = blockIdx.x * blockDim.x + threadIdx.x;
    if (idx >= LL * CC) return;
    int c = idx % CC;
    int l = idx / CC;
    out[l * CC + c] = xafter[l * CC + c] * skip2[c] + t2[c * LL + l] * v2[c];
}

// ---------------- workspace layout (float offsets) ----------------
static const size_t OFF_XS     = 0;          // 8*96*8192 (xs -> ys; conv partials after combine)
static const size_t OFF_Z      = 6291456;    // 786432 (z channel-major)
static const size_t OFF_XCM    = 7077888;    // 786432 (pre-conv x; reused as acc)
static const size_t OFF_XN     = 7864320;    // 786432 (xn_cm; reused as y)
static const size_t OFF_DTRAW  = 8650752;    // 393216
static const size_t OFF_BB     = 9043968;    // 1048576
static const size_t OFF_CB     = 10092544;   // 1048576
static const size_t OFF_XAFTER = 11141120;   // 786432 (scan: Ap reuses this)
static const size_t OFF_Y2     = 11927552;   // 786432 (scan: Bc reuses this)
static const size_t OFF_T1     = 12713984;   // 262144
static const size_t OFF_T2     = 12976128;   // 786432 (scan: hs reuses this)
static const size_t OFF_MV     = 13762560;   // 256
static const size_t OFF_WT1    = 13762816;   // 82944
static const size_t OFF_WT2    = 13845760;   // 82944
static const size_t OFF_IPT    = 13928704;   // 18432
static const size_t OFF_XPT    = 13947136;   // 29184  (end ~13976320 fl = 55.9 MB)

extern "C" void kernel_launch(void* const* d_in, const int* in_sizes, int n_in,
                              void* d_out, int out_size, void* d_ws, size_t ws_size,
                              hipStream_t stream) {
    const float* inp    = (const float*)d_in[0];
    const float* ln1_w  = (const float*)d_in[2];
    const float* ln1_b  = (const float*)d_in[3];
    const float* skip1  = (const float*)d_in[4];
    const float* skip2  = (const float*)d_in[5];
    const float* ln2_w  = (const float*)d_in[6];
    const float* ln2_b  = (const float*)d_in[7];
    const float* inpj   = (const float*)d_in[8];
    const float* conv_w = (const float*)d_in[9];
    const float* conv_b = (const float*)d_in[10];
    const float* xpw    = (const float*)d_in[11];
    const float* dt_w   = (const float*)d_in[12];
    const float* dt_b   = (const float*)d_in[13];
    const float* A_logs = (const float*)d_in[14];
    const float* Ds     = (const float*)d_in[15];
    const float* onw    = (const float*)d_in[16];
    const float* onb    = (const float*)d_in[17];
    const float* opw    = (const float*)d_in[18];
    const float* cab_w1 = (const float*)d_in[19];
    const float* cab_b1 = (const float*)d_in[20];
    const float* cab_w2 = (const float*)d_in[21];
    const float* cab_b2 = (const float*)d_in[22];
    const float* ca_w1  = (const float*)d_in[23];
    const float* ca_b1  = (const float*)d_in[24];
    const float* ca_w2  = (const float*)d_in[25];
    const float* ca_b2  = (const float*)d_in[26];

    float* ws = (float*)d_ws;
    float* xs     = ws + OFF_XS;
    float* zbuf   = ws + OFF_Z;
    float* xcm    = ws + OFF_XCM;
    float* xn     = ws + OFF_XN;
    float* dtraw  = ws + OFF_DTRAW;
    float* Bb     = ws + OFF_BB;
    float* Cb     = ws + OFF_CB;
    float* xafter = ws + OFF_XAFTER;
    float* y2     = ws + OFF_Y2;
    float* t1     = ws + OFF_T1;
    float* t2     = ws + OFF_T2;
    float* mv     = ws + OFF_MV;
    float* wT1    = ws + OFF_WT1;
    float* wT2    = ws + OFF_WT2;
    float* ipT    = ws + OFF_IPT;
    float* xpT    = ws + OFF_XPT;
    float* acc    = xcm;                 // reuse (xcm dead after dwconv)
    float* ybuf   = xn;                  // reuse (xn dead after inproj)
    float* Ap     = xafter;              // reuse (xafter written at k_outproj)
    float* Bc     = y2;                  // reuse (y2 written at k_ln2)
    float* hst    = t2;                  // reuse (t2 written at k_conv2sum)
    float* part1  = xs;                  // 8*32*8192 (xs dead after combine)
    float* part2  = xs + 2097152;        // 4*96*8192

    float* out = (float*)d_out;
    #define GRID(n) dim3((unsigned)(((n) + 255) / 256)), dim3(256)

    hipLaunchKernelGGL(k_ln1,     GRID(LL),                   0, stream, inp, ln1_w, ln1_b, xn);
    hipLaunchKernelGGL(k_wtrans,  GRID(82944),                0, stream, inpj, xpw, cab_w1, cab_w2, ipT, xpT, wT1, wT2);
    hipLaunchKernelGGL(k_inproj,  dim3(768), dim3(256),       0, stream, xn, ipT, xcm, zbuf);
    hipLaunchKernelGGL(k_dwconv,  GRID(DINc * LL),            0, stream, xcm, conv_w, conv_b, xs);
    hipLaunchKernelGGL(k_perm,    GRID(7 * DINc * LL),        0, stream, xs);
    hipLaunchKernelGGL(k_xdbl,    dim3(256), dim3(256),       0, stream, xs, xpT, dtraw, Bb, Cb);
    hipLaunchKernelGGL(k_scan1,   GRID(KK * DINc * NCH * NN), 0, stream, xs, dtraw, Bb, A_logs, dt_w, dt_b, Ap, Bc);
    hipLaunchKernelGGL(k_scan2,   GRID(KK * DINc * NN),       0, stream, Ap, Bc, hst);
    hipLaunchKernelGGL(k_scan3,   GRID(KK * DINc * NCH * NN), 0, stream, xs, dtraw, Bb, Cb, A_logs, dt_w, dt_b, Ds, hst);
    hipLaunchKernelGGL(k_combine, GRID(LL * DINc),            0, stream, xs, acc);
    hipLaunchKernelGGL(k_outnorm, GRID(LL),                   0, stream, acc, zbuf, onw, onb, ybuf);
    hipLaunchKernelGGL(k_outproj, GRID(LL * CC),              0, stream, ybuf, opw, inp, skip1, xafter);
    hipLaunchKernelGGL(k_ln2,     GRID(LL),                   0, stream, xafter, ln2_w, ln2_b, y2);
    hipLaunchKernelGGL(k_conv1,   dim3(1024), dim3(256),      0, stream, y2, wT1, part1);
    hipLaunchKernelGGL(k_gelusum, GRID(32 * LL),              0, stream, part1, cab_b1, t1);
    hipLaunchKernelGGL(k_conv2,   dim3(1536), dim3(256),      0, stream, t1, wT2, part2);
    hipLaunchKernelGGL(k_conv2sum,GRID(96 * LL),              0, stream, part2, cab_b2, t2);
    hipLaunchKernelGGL(k_mean,    dim3(96), dim3(256),        0, stream, t2, mv);
    hipLaunchKernelGGL(k_mlp,     dim3(1), dim3(128),         0, stream, mv, ca_w1, ca_b1, ca_w2, ca_b2, mv + 96);
    hipLaunchKernelGGL(k_final,   GRID(LL * CC),              0, stream, xafter, skip2, t2, mv + 96, out);
    #undef GRID
}

// Round 8
// 395.670 us; speedup vs baseline: 1.2104x; 1.2104x over previous
//
#include <hip/hip_runtime.h>
#include <math.h>

#define LL 8192
#define CC 96
#define DINc 96
#define NN 16
#define RR 6
#define KK 8
#define Dd 16
#define Hh 16
#define Ww 32
#define NCH 32
#define CHL 256   // LL / NCH

__constant__ int Pc_[4][3] = {{0,1,2},{1,2,0},{2,0,1},{2,1,0}};

__device__ __forceinline__ float silu_(float x){ return x / (1.f + __expf(-x)); }

// ---------------- K1: LN over C at each l -> xn CHANNEL-MAJOR [c][l] ----------------
__global__ void k_ln1(const float* __restrict__ inp, const float* __restrict__ w,
                      const float* __restrict__ b, float* __restrict__ xn_cm) {
    int l = blockIdx.x * blockDim.x + threadIdx.x;
    if (l >= LL) return;
    const float* p = inp + l * CC;
    float m = 0.f;
    for (int c = 0; c < CC; ++c) m += p[c];
    m *= (1.f / CC);
    float v = 0.f;
    for (int c = 0; c < CC; ++c) { float d = p[c] - m; v += d * d; }
    v *= (1.f / CC);
    float r = rsqrtf(v + 1e-6f);
    for (int c = 0; c < CC; ++c) xn_cm[c * LL + l] = (p[c] - m) * r * w[c] + b[c];
}

// ---------------- KW: transpose weights (in_proj, x_proj, cab convs) ----------------
__global__ void k_wtrans(const float* __restrict__ inpj, const float* __restrict__ xpw,
                         const float* __restrict__ w1, const float* __restrict__ w2,
                         float* __restrict__ ipT, float* __restrict__ xpT,
                         float* __restrict__ wT1, float* __restrict__ wT2) {
    int idx = blockIdx.x * blockDim.x + threadIdx.x;
    if (idx < 82944) {   // wT1: [ic][tap][oc=32]
        int oc = idx & 31; int tap = (idx >> 5) % 27; int ic = idx / (32 * 27);
        wT1[idx] = w1[(oc * 96 + ic) * 27 + tap];
    }
    if (idx < 82944) {   // wT2: [ic][tap][oc=96]
        int oc = idx % 96; int tap = (idx / 96) % 27; int ic = idx / (96 * 27);
        wT2[idx] = w2[(oc * 32 + ic) * 27 + tap];
    }
    if (idx < 18432) {   // ipT: [c][e=192]
        int e = idx % 192; int c = idx / 192;
        ipT[idx] = inpj[e * 96 + c];
    }
    if (idx < 29184) {   // xpT: [k][c][e=38]
        int e = idx % 38; int c = (idx / 38) % 96; int k = idx / (38 * 96);
        xpT[idx] = xpw[(k * 38 + e) * 96 + c];
    }
}

// ---------------- K2: in_proj, 8-e register block, uniform weights ----------------
__global__ void k_inproj(const float* __restrict__ xn_cm, const float* __restrict__ ipT,
                         float* __restrict__ xcm, float* __restrict__ z_cm) {
    int bx = blockIdx.x;
    int eb = bx >> 5;                       // 0..23 (uniform)
    int l  = ((bx & 31) << 8) + threadIdx.x;
    int e0 = eb << 3;
    float a[8];
    #pragma unroll
    for (int j = 0; j < 8; ++j) a[j] = 0.f;
    const float* wp = ipT + e0;
    for (int c = 0; c < CC; ++c) {
        float x = xn_cm[c * LL + l];
        const float4* wv = (const float4*)(wp + c * 192);
        float4 wa = wv[0], wb = wv[1];
        a[0] += x * wa.x; a[1] += x * wa.y; a[2] += x * wa.z; a[3] += x * wa.w;
        a[4] += x * wb.x; a[5] += x * wb.y; a[6] += x * wb.z; a[7] += x * wb.w;
    }
    float* dst = (e0 < DINc) ? (xcm + (long)e0 * LL) : (z_cm + (long)(e0 - DINc) * LL);
    #pragma unroll
    for (int j = 0; j < 8; ++j) dst[(long)j * LL + l] = a[j];
}

// ---------------- K3: depthwise conv3d + SiLU -> xs[0] ----------------
__global__ void k_dwconv(const float* __restrict__ xcm, const float* __restrict__ cw,
                         const float* __restrict__ cb, float* __restrict__ xs0) {
    int idx = blockIdx.x * blockDim.x + threadIdx.x;
    if (idx >= DINc * LL) return;
    int l = idx & (LL - 1);
    int c = idx >> 13;
    int w = l & (Ww - 1);
    int h = (l >> 5) & (Hh - 1);
    int d = l >> 9;
    float s = cb[c];
    const float* xp = xcm + c * LL;
    const float* wp = cw + c * 27;
    for (int kd = -1; kd <= 1; ++kd) {
        int dd = d + kd; if ((unsigned)dd >= Dd) continue;
        for (int kh = -1; kh <= 1; ++kh) {
            int hh = h + kh; if ((unsigned)hh >= Hh) continue;
            for (int kw = -1; kw <= 1; ++kw) {
                int ww2 = w + kw; if ((unsigned)ww2 >= Ww) continue;
                s += xp[(dd * Hh + hh) * Ww + ww2] * wp[(kd + 1) * 9 + (kh + 1) * 3 + (kw + 1)];
            }
        }
    }
    xs0[c * LL + l] = silu_(s);
}

// ---------------- K4: build xs[1..7] ----------------
__global__ void k_perm(float* __restrict__ xs) {
    int idx = blockIdx.x * blockDim.x + threadIdx.x;
    if (idx >= 7 * DINc * LL) return;
    int l = idx & (LL - 1);
    int c = (idx >> 13) % DINc;
    int k = idx / (DINc * LL) + 1;
    int i  = (k < 4) ? k : (k - 4);
    int lp = (k < 4) ? l : (LL - 1 - l);
    int p0 = Pc_[i][0], p1 = Pc_[i][1], p2 = Pc_[i][2];
    const int sp[3] = {Dd, Hh, Ww};
    int pd1 = sp[p1], pd2 = sp[p2];
    int i2 = lp % pd2;
    int t  = lp / pd2;
    int i1 = t % pd1;
    int i0 = t / pd1;
    int coord[3];
    coord[p0] = i0; coord[p1] = i1; coord[p2] = i2;
    int o = (coord[0] * Hh + coord[1]) * Ww + coord[2];
    xs[(k * DINc + c) * LL + l] = xs[c * LL + o];
}

// ---------------- K5: x_dbl, 38 accumulators per (k,l), xs read once ----------------
__global__ void k_xdbl(const float* __restrict__ xs, const float* __restrict__ xpT,
                       float* __restrict__ dtraw, float* __restrict__ Bb, float* __restrict__ Cb) {
    int bx = blockIdx.x;
    int k = bx >> 5;                        // uniform
    int l = ((bx & 31) << 8) + threadIdx.x;
    float acc[38];
    #pragma unroll
    for (int e = 0; e < 38; ++e) acc[e] = 0.f;
    const float* xb = xs + (long)k * DINc * LL + l;
    const float* wb = xpT + k * DINc * 38;
    for (int c = 0; c < DINc; ++c) {
        float x = xb[(long)c * LL];
        const float* wr = wb + c * 38;
        #pragma unroll
        for (int e = 0; e < 38; ++e) acc[e] += x * wr[e];
    }
    #pragma unroll
    for (int r = 0; r < RR; ++r) dtraw[(k * RR + r) * LL + l] = acc[r];
    float* Bp = Bb + ((long)k * LL + l) * NN;
    float* Cp = Cb + ((long)k * LL + l) * NN;
    #pragma unroll
    for (int n = 0; n < NN; ++n) { Bp[n] = acc[RR + n]; Cp[n] = acc[RR + NN + n]; }
}

// ---------------- softplus ----------------
__device__ __forceinline__ float softplus_(float x) {
    return (x > 20.f) ? x : __logf(1.f + __expf(x));
}

// ---------------- K7a: chunk-local scan -> (Aprod, Bacc); LDS (dt,du) pair broadcast ----------------
__global__ void k_scan1(const float* __restrict__ xs, const float* __restrict__ dtraw,
                        const float* __restrict__ Bb, const float* __restrict__ A_logs,
                        const float* __restrict__ dt_w, const float* __restrict__ dt_b,
                        float* __restrict__ Ap, float* __restrict__ Bc) {
    __shared__ float2 sdu[256];
    int t = blockIdx.x * blockDim.x + threadIdx.x;
    int n = t & 15;
    int gc = t >> 4;
    if (gc >= KK * DINc * NCH) return;
    int gbase = threadIdx.x & ~15;
    int grp = gc >> 5;
    int chunk = gc & (NCH - 1);
    int k = grp / DINc;
    float A_n = -__expf(A_logs[grp * NN + n]);
    float w0 = dt_w[grp * RR + 0], w1 = dt_w[grp * RR + 1], w2 = dt_w[grp * RR + 2];
    float w3 = dt_w[grp * RR + 3], w4 = dt_w[grp * RR + 4], w5 = dt_w[grp * RR + 5];
    float dtb = dt_b[grp];
    const float* drb  = dtraw + (long)k * RR * LL + chunk * CHL;
    const float* urow = xs + (long)grp * LL + chunk * CHL;
    const float* Bblk = Bb + ((long)k * LL + chunk * CHL) * NN + n;
    float hc = 0.f, dsuml = 0.f;
    for (int base = 0; base < CHL; base += 16) {
        int lm = base + n;
        float dtl = dtb + drb[lm] * w0 + drb[LL + lm] * w1 + drb[2 * LL + lm] * w2
                        + drb[3 * LL + lm] * w3 + drb[4 * LL + lm] * w4 + drb[5 * LL + lm] * w5;
        float dt_lane = softplus_(dtl);
        float u_lane  = urow[lm];
        sdu[threadIdx.x] = make_float2(dt_lane, dt_lane * u_lane);
        dsuml += dt_lane;
        #pragma unroll
        for (int j = 0; j < 16; ++j) {
            float2 v = sdu[gbase + j];
            float a  = __expf(v.x * A_n);
            hc = a * hc + v.y * Bblk[(base + j) * NN];
        }
    }
    dsuml += __shfl_xor(dsuml, 1, 16);
    dsuml += __shfl_xor(dsuml, 2, 16);
    dsuml += __shfl_xor(dsuml, 4, 16);
    dsuml += __shfl_xor(dsuml, 8, 16);
    int o = (grp * NN + n) * NCH + chunk;
    Ap[o] = __expf(A_n * dsuml);
    Bc[o] = hc;
}

// ---------------- K7b: combine chunk transfers ----------------
__global__ void k_scan2(const float* __restrict__ Ap, const float* __restrict__ Bc,
                        float* __restrict__ hs) {
    int t = blockIdx.x * blockDim.x + threadIdx.x;
    if (t >= KK * DINc * NN) return;
    int base = t * NCH;
    float h = 0.f;
    for (int c = 0; c < NCH; ++c) {
        hs[base + c] = h;
        h = Ap[base + c] * h + Bc[base + c];
    }
}

// ---------------- K7c: final scan; LDS pair broadcast + deferred 4-stage tree reduce ----------------
__global__ void k_scan3(float* __restrict__ xs_ys, const float* __restrict__ dtraw,
                        const float* __restrict__ Bb, const float* __restrict__ Cb,
                        const float* __restrict__ A_logs, const float* __restrict__ dt_w,
                        const float* __restrict__ dt_b, const float* __restrict__ Ds,
                        const float* __restrict__ hs) {
    __shared__ float2 sdu[256];
    int t = blockIdx.x * blockDim.x + threadIdx.x;
    int n = t & 15;
    int gc = t >> 4;
    if (gc >= KK * DINc * NCH) return;
    int gbase = threadIdx.x & ~15;
    int grp = gc >> 5;
    int chunk = gc & (NCH - 1);
    int k = grp / DINc;
    float A_n = -__expf(A_logs[grp * NN + n]);
    float w0 = dt_w[grp * RR + 0], w1 = dt_w[grp * RR + 1], w2 = dt_w[grp * RR + 2];
    float w3 = dt_w[grp * RR + 3], w4 = dt_w[grp * RR + 4], w5 = dt_w[grp * RR + 5];
    float dtb = dt_b[grp];
    float Dv  = Ds[grp];
    const float* drb  = dtraw + (long)k * RR * LL + chunk * CHL;
    const float* Bblk = Bb + ((long)k * LL + chunk * CHL) * NN + n;
    const float* Cblk = Cb + ((long)k * LL + chunk * CHL) * NN + n;
    float* urow = xs_ys + (long)grp * LL + chunk * CHL;
    float hc = hs[(grp * NN + n) * NCH + chunk];
    bool b0 = (n & 1), b1 = ((n >> 1) & 1), b2 = ((n >> 2) & 1), b3 = (n >> 3);
    for (int base = 0; base < CHL; base += 16) {
        int lm = base + n;
        float dtl = dtb + drb[lm] * w0 + drb[LL + lm] * w1 + drb[2 * LL + lm] * w2
                        + drb[3 * LL + lm] * w3 + drb[4 * LL + lm] * w4 + drb[5 * LL + lm] * w5;
        float dt_lane = softplus_(dtl);
        float u_lane  = urow[lm];
        sdu[threadIdx.x] = make_float2(dt_lane, dt_lane * u_lane);
        float p[16];
        #pragma unroll
        for (int j = 0; j < 16; ++j) {
            float2 v = sdu[gbase + j];
            float a  = __expf(v.x * A_n);
            hc = a * hc + v.y * Bblk[(base + j) * NN];
            p[j] = hc * Cblk[(base + j) * NN];
        }
        float q[8];
        #pragma unroll
        for (int m = 0; m < 8; ++m) {
            float s = b0 ? p[2*m] : p[2*m+1];
            float r = __shfl_xor(s, 1, 16);
            q[m] = (b0 ? p[2*m+1] : p[2*m]) + r;
        }
        float r4[4];
        #pragma unroll
        for (int m = 0; m < 4; ++m) {
            float s = b1 ? q[2*m] : q[2*m+1];
            float r = __shfl_xor(s, 2, 16);
            r4[m] = (b1 ? q[2*m+1] : q[2*m]) + r;
        }
        float t2r[2];
        #pragma unroll
        for (int m = 0; m < 2; ++m) {
            float s = b2 ? r4[2*m] : r4[2*m+1];
            float r = __shfl_xor(s, 4, 16);
            t2r[m] = (b2 ? r4[2*m+1] : r4[2*m]) + r;
        }
        float s = b3 ? t2r[0] : t2r[1];
        float r = __shfl_xor(s, 8, 16);
        float yv = (b3 ? t2r[1] : t2r[0]) + r;
        urow[base + n] = yv + Dv * u_lane;
    }
}

// ---------------- K8: inverse-permute + sum 8 directions ----------------
__global__ void k_combine(const float* __restrict__ ys, float* __restrict__ acc) {
    int idx = blockIdx.x * blockDim.x + threadIdx.x;
    if (idx >= LL * DINc) return;
    int c = idx % DINc;
    int l = idx / DINc;
    int w = l & (Ww - 1);
    int h = (l >> 5) & (Hh - 1);
    int d = l >> 9;
    int coord[3] = {d, h, w};
    const int sp[3] = {Dd, Hh, Ww};
    float s = 0.f;
    #pragma unroll
    for (int i = 0; i < 4; ++i) {
        int p0 = Pc_[i][0], p1 = Pc_[i][1], p2 = Pc_[i][2];
        int lp = (coord[p0] * sp[p1] + coord[p1]) * sp[p2] + coord[p2];
        s += ys[(long)(i * DINc + c) * LL + lp];
        s += ys[(long)((4 + i) * DINc + c) * LL + (LL - 1 - lp)];
    }
    acc[l * DINc + c] = s;
}

// ---------------- K9: out_norm LN * silu(z_cm) ----------------
__global__ void k_outnorm(const float* __restrict__ acc, const float* __restrict__ z_cm,
                          const float* __restrict__ w, const float* __restrict__ b,
                          float* __restrict__ y) {
    int l = blockIdx.x * blockDim.x + threadIdx.x;
    if (l >= LL) return;
    const float* a = acc + l * DINc;
    float m = 0.f;
    for (int c = 0; c < DINc; ++c) m += a[c];
    m *= (1.f / DINc);
    float v = 0.f;
    for (int c = 0; c < DINc; ++c) { float d = a[c] - m; v += d * d; }
    v *= (1.f / DINc);
    float r = rsqrtf(v + 1e-5f);
    for (int c = 0; c < DINc; ++c) {
        float zz = z_cm[(long)c * LL + l];
        y[l * DINc + c] = ((a[c] - m) * r * w[c] + b[c]) * silu_(zz);
    }
}

// ---------------- K10: out_proj + skip1 ----------------
__global__ void k_outproj(const float* __restrict__ y, const float* __restrict__ opw,
                          const float* __restrict__ inp, const float* __restrict__ skip1,
                          float* __restrict__ xafter) {
    int idx = blockIdx.x * blockDim.x + threadIdx.x;
    if (idx >= LL * CC) return;
    int c = idx % CC;
    int l = idx / CC;
    const float* yr = y + l * DINc;
    const float* wr = opw + c * DINc;
    float s = 0.f;
    for (int e = 0; e < DINc; ++e) s += yr[e] * wr[e];
    xafter[l * CC + c] = inp[l * CC + c] * skip1[c] + s;
}

// ---------------- K11: LN2 -> channel-major ----------------
__global__ void k_ln2(const float* __restrict__ xafter, const float* __restrict__ w,
                      const float* __restrict__ b, float* __restrict__ y2) {
    int l = blockIdx.x * blockDim.x + threadIdx.x;
    if (l >= LL) return;
    const float* p = xafter + l * CC;
    float m = 0.f;
    for (int c = 0; c < CC; ++c) m += p[c];
    m *= (1.f / CC);
    float v = 0.f;
    for (int c = 0; c < CC; ++c) { float d = p[c] - m; v += d * d; }
    v *= (1.f / CC);
    float r = rsqrtf(v + 1e-5f);
    for (int c = 0; c < CC; ++c) y2[c * LL + l] = (p[c] - m) * r * w[c] + b[c];
}

// ---------------- K12: conv3d 96->32, 4-wide w-vectorized, 16-way ic-split ----------------
// grid 512: bx>>3 = g (ocg = g&3, isp = g>>2, 6 ic each); l4 = (bx&7)*256+tid
__global__ void k_conv1(const float* __restrict__ y2, const float* __restrict__ wT,
                        float* __restrict__ part) {
    int bx = blockIdx.x;
    int g  = bx >> 3;
    int ocg = g & 3;
    int isp = g >> 2;
    int l4 = ((bx & 7) << 8) + threadIdx.x;
    int w0 = (l4 & 7) << 2;
    int h  = (l4 >> 3) & 15;
    int d  = l4 >> 7;
    int l  = (d * Hh + h) * Ww + w0;
    float rmask[9]; int roff[9];
    #pragma unroll
    for (int kd = 0; kd < 3; ++kd) {
        int dd = d + kd - 1;
        bool vd = (unsigned)dd < Dd; int dc = vd ? dd : 0;
        #pragma unroll
        for (int kh = 0; kh < 3; ++kh) {
            int hh = h + kh - 1;
            bool vh = (unsigned)hh < Hh; int hcl = vh ? hh : 0;
            rmask[kd * 3 + kh] = (vd && vh) ? 1.f : 0.f;
            roff[kd * 3 + kh]  = (dc * Hh + hcl) * Ww + w0;
        }
    }
    float mleft  = (w0 > 0)  ? 1.f : 0.f;
    float mright = (w0 < 28) ? 1.f : 0.f;
    float acc[32];
    #pragma unroll
    for (int j = 0; j < 32; ++j) acc[j] = 0.f;
    for (int ic = isp * 6; ic < isp * 6 + 6; ++ic) {
        const float* xp = y2 + (long)ic * LL;
        const float* wb = wT + ic * 864 + ocg * 8;
        #pragma unroll
        for (int r = 0; r < 9; ++r) {
            float rm = rmask[r];
            const float* xr = xp + roff[r];
            float4 xc = *(const float4*)xr;
            float v[6];
            v[0] = xr[-1] * (rm * mleft);
            v[1] = xc.x * rm; v[2] = xc.y * rm; v[3] = xc.z * rm; v[4] = xc.w * rm;
            v[5] = xr[4] * (rm * mright);
            #pragma unroll
            for (int t = 0; t < 3; ++t) {
                const float4* wv = (const float4*)(wb + (r * 3 + t) * 32);
                float4 wa = wv[0], wbv = wv[1];
                #pragma unroll
                for (int p = 0; p < 4; ++p) {
                    float x = v[t + p];
                    acc[0  + p] += x * wa.x;  acc[4  + p] += x * wa.y;
                    acc[8  + p] += x * wa.z;  acc[12 + p] += x * wa.w;
                    acc[16 + p] += x * wbv.x; acc[20 + p] += x * wbv.y;
                    acc[24 + p] += x * wbv.z; acc[28 + p] += x * wbv.w;
                }
            }
        }
    }
    float* pp = part + ((long)(isp * 32 + ocg * 8)) * LL + l;
    #pragma unroll
    for (int oc = 0; oc < 8; ++oc)
        *(float4*)(pp + (long)oc * LL) = make_float4(acc[oc*4+0], acc[oc*4+1], acc[oc*4+2], acc[oc*4+3]);
}

// ---------------- K12b: t1 = GELU(sum 16 partials + bias) ----------------
__global__ void k_gelusum(const float* __restrict__ part, const float* __restrict__ b1,
                          float* __restrict__ t1) {
    int idx = blockIdx.x * blockDim.x + threadIdx.x;
    if (idx >= 32 * LL) return;
    int l = idx & (LL - 1);
    int oc = idx >> 13;
    float s = b1[oc];
    #pragma unroll
    for (int isp = 0; isp < 16; ++isp)
        s += part[((long)(isp * 32 + oc)) * LL + l];
    t1[oc * LL + l] = 0.5f * s * (1.f + erff(s * 0.70710678118654752f));
}

// ---------------- K13: conv3d 32->96, 4-wide w-vectorized, 8-way ic-split ----------------
// grid 768: g = bx>>3 (ocg = g%12, isp = g/12, 4 ic each); l4 = (bx&7)*256+tid
__global__ void k_conv2(const float* __restrict__ t1, const float* __restrict__ wT,
                        float* __restrict__ part) {
    int bx = blockIdx.x;
    int g  = bx >> 3;
    int ocg = g % 12;
    int isp = g / 12;
    int l4 = ((bx & 7) << 8) + threadIdx.x;
    int w0 = (l4 & 7) << 2;
    int h  = (l4 >> 3) & 15;
    int d  = l4 >> 7;
    int l  = (d * Hh + h) * Ww + w0;
    float rmask[9]; int roff[9];
    #pragma unroll
    for (int kd = 0; kd < 3; ++kd) {
        int dd = d + kd - 1;
        bool vd = (unsigned)dd < Dd; int dc = vd ? dd : 0;
        #pragma unroll
        for (int kh = 0; kh < 3; ++kh) {
            int hh = h + kh - 1;
            bool vh = (unsigned)hh < Hh; int hcl = vh ? hh : 0;
            rmask[kd * 3 + kh] = (vd && vh) ? 1.f : 0.f;
            roff[kd * 3 + kh]  = (dc * Hh + hcl) * Ww + w0;
        }
    }
    float mleft  = (w0 > 0)  ? 1.f : 0.f;
    float mright = (w0 < 28) ? 1.f : 0.f;
    float acc[32];
    #pragma unroll
    for (int j = 0; j < 32; ++j) acc[j] = 0.f;
    for (int ic = isp * 4; ic < isp * 4 + 4; ++ic) {
        const float* xp = t1 + (long)ic * LL;
        const float* wb = wT + ic * 2592 + ocg * 8;
        #pragma unroll
        for (int r = 0; r < 9; ++r) {
            float rm = rmask[r];
            const float* xr = xp + roff[r];
            float4 xc = *(const float4*)xr;
            float v[6];
            v[0] = xr[-1] * (rm * mleft);
            v[1] = xc.x * rm; v[2] = xc.y * rm; v[3] = xc.z * rm; v[4] = xc.w * rm;
            v[5] = xr[4] * (rm * mright);
            #pragma unroll
            for (int t = 0; t < 3; ++t) {
                const float4* wv = (const float4*)(wb + (r * 3 + t) * 96);
                float4 wa = wv[0], wbv = wv[1];
                #pragma unroll
                for (int p = 0; p < 4; ++p) {
                    float x = v[t + p];
                    acc[0  + p] += x * wa.x;  acc[4  + p] += x * wa.y;
                    acc[8  + p] += x * wa.z;  acc[12 + p] += x * wa.w;
                    acc[16 + p] += x * wbv.x; acc[20 + p] += x * wbv.y;
                    acc[24 + p] += x * wbv.z; acc[28 + p] += x * wbv.w;
                }
            }
        }
    }
    float* pp = part + ((long)(isp * 96 + ocg * 8)) * LL + l;
    #pragma unroll
    for (int oc = 0; oc < 8; ++oc)
        *(float4*)(pp + (long)oc * LL) = make_float4(acc[oc*4+0], acc[oc*4+1], acc[oc*4+2], acc[oc*4+3]);
}

// ---------------- K13b: t2 = sum 8 partials + bias ----------------
__global__ void k_conv2sum(const float* __restrict__ part, const float* __restrict__ b2,
                           float* __restrict__ t2) {
    int idx = blockIdx.x * blockDim.x + threadIdx.x;
    if (idx >= 96 * LL) return;
    int l = idx & (LL - 1);
    int oc = idx >> 13;
    float s = b2[oc];
    #pragma unroll
    for (int isp = 0; isp < 8; ++isp)
        s += part[((long)(isp * 96 + oc)) * LL + l];
    t2[oc * LL + l] = s;
}

// ---------------- K14a: per-channel mean ----------------
__global__ void k_mean(const float* __restrict__ t2, float* __restrict__ mbuf) {
    __shared__ float sm[256];
    int c = blockIdx.x;
    float a = 0.f;
    for (int l = threadIdx.x; l < LL; l += 256) a += t2[c * LL + l];
    sm[threadIdx.x] = a;
    __syncthreads();
    for (int o = 128; o > 0; o >>= 1) {
        if (threadIdx.x < o) sm[threadIdx.x] += sm[threadIdx.x + o];
        __syncthreads();
    }
    if (threadIdx.x == 0) mbuf[c] = sm[0] * (1.f / LL);
}

// ---------------- K14b: channel-attention MLP ----------------
__global__ void k_mlp(const float* __restrict__ mbuf, const float* __restrict__ w1,
                      const float* __restrict__ b1, const float* __restrict__ w2,
                      const float* __restrict__ b2, float* __restrict__ v2) {
    __shared__ float v[48];
    int t = threadIdx.x;
    if (t < 48) {
        float s = b1[t];
        for (int c = 0; c < 96; ++c) s += mbuf[c] * w1[t * 96 + c];
        v[t] = fmaxf(s, 0.f);
    }
    __syncthreads();
    if (t < 96) {
        float s = b2[t];
        for (int j = 0; j < 48; ++j) s += v[j] * w2[t * 48 + j];
        v2[t] = 1.f / (1.f + __expf(-s));
    }
}

// ---------------- K15: final residual ----------------
__global__ void k_final(const float* __restrict__ xafter, const float* __restrict__ skip2,
                        const float* __restrict__ t2, const float* __restrict__ v2,
                        float* __restrict__ out) {
    int idx = blockIdx.x * blockDim.x + threadIdx.x;
    if (idx >= LL * CC) return;
    int c = idx % CC;
    int l = idx / CC;
    out[l * CC + c] = xafter[l * CC + c] * skip2[c] + t2[c * LL + l] * v2[c];
}

// ---------------- workspace layout (float offsets) ----------------
static const size_t OFF_XS     = 0;          // 8*96*8192 (xs -> ys; conv partials after combine)
static const size_t OFF_Z      = 6291456;    // 786432 (z channel-major)
static const size_t OFF_XCM    = 7077888;    // 786432 (pre-conv x; reused as acc)
static const size_t OFF_XN     = 7864320;    // 786432 (xn_cm; reused as y)
static const size_t OFF_DTRAW  = 8650752;    // 393216
static const size_t OFF_BB     = 9043968;    // 1048576
static const size_t OFF_CB     = 10092544;   // 1048576
static const size_t OFF_XAFTER = 11141120;   // 786432 (scan: Ap reuses this)
static const size_t OFF_Y2     = 11927552;   // 786432 (scan: Bc reuses this)
static const size_t OFF_T1     = 12713984;   // 262144
static const size_t OFF_T2     = 12976128;   // 786432 (scan: hs reuses this)
static const size_t OFF_MV     = 13762560;   // 256
static const size_t OFF_WT1    = 13762816;   // 82944
static const size_t OFF_WT2    = 13845760;   // 82944
static const size_t OFF_IPT    = 13928704;   // 18432
static const size_t OFF_XPT    = 13947136;   // 29184  (end ~13976320 fl = 55.9 MB)

extern "C" void kernel_launch(void* const* d_in, const int* in_sizes, int n_in,
                              void* d_out, int out_size, void* d_ws, size_t ws_size,
                              hipStream_t stream) {
    const float* inp    = (const float*)d_in[0];
    const float* ln1_w  = (const float*)d_in[2];
    const float* ln1_b  = (const float*)d_in[3];
    const float* skip1  = (const float*)d_in[4];
    const float* skip2  = (const float*)d_in[5];
    const float* ln2_w  = (const float*)d_in[6];
    const float* ln2_b  = (const float*)d_in[7];
    const float* inpj   = (const float*)d_in[8];
    const float* conv_w = (const float*)d_in[9];
    const float* conv_b = (const float*)d_in[10];
    const float* xpw    = (const float*)d_in[11];
    const float* dt_w   = (const float*)d_in[12];
    const float* dt_b   = (const float*)d_in[13];
    const float* A_logs = (const float*)d_in[14];
    const float* Ds     = (const float*)d_in[15];
    const float* onw    = (const float*)d_in[16];
    const float* onb    = (const float*)d_in[17];
    const float* opw    = (const float*)d_in[18];
    const float* cab_w1 = (const float*)d_in[19];
    const float* cab_b1 = (const float*)d_in[20];
    const float* cab_w2 = (const float*)d_in[21];
    const float* cab_b2 = (const float*)d_in[22];
    const float* ca_w1  = (const float*)d_in[23];
    const float* ca_b1  = (const float*)d_in[24];
    const float* ca_w2  = (const float*)d_in[25];
    const float* ca_b2  = (const float*)d_in[26];

    float* ws = (float*)d_ws;
    float* xs     = ws + OFF_XS;
    float* zbuf   = ws + OFF_Z;
    float* xcm    = ws + OFF_XCM;
    float* xn     = ws + OFF_XN;
    float* dtraw  = ws + OFF_DTRAW;
    float* Bb     = ws + OFF_BB;
    float* Cb     = ws + OFF_CB;
    float* xafter = ws + OFF_XAFTER;
    float* y2     = ws + OFF_Y2;
    float* t1     = ws + OFF_T1;
    float* t2     = ws + OFF_T2;
    float* mv     = ws + OFF_MV;
    float* wT1    = ws + OFF_WT1;
    float* wT2    = ws + OFF_WT2;
    float* ipT    = ws + OFF_IPT;
    float* xpT    = ws + OFF_XPT;
    float* acc    = xcm;                 // reuse (xcm dead after dwconv)
    float* ybuf   = xn;                  // reuse (xn dead after inproj)
    float* Ap     = xafter;              // reuse (xafter written at k_outproj)
    float* Bc     = y2;                  // reuse (y2 written at k_ln2)
    float* hst    = t2;                  // reuse (t2 written at k_conv2sum)
    float* part1  = xs;                  // 16*32*8192 = 4194304 (xs dead after combine)
    float* part2  = xs;                  // 8*96*8192 = 6291456 (aliases part1; part1 dead after gelusum)

    float* out = (float*)d_out;
    #define GRID(n) dim3((unsigned)(((n) + 255) / 256)), dim3(256)

    hipLaunchKernelGGL(k_ln1,     GRID(LL),                   0, stream, inp, ln1_w, ln1_b, xn);
    hipLaunchKernelGGL(k_wtrans,  GRID(82944),                0, stream, inpj, xpw, cab_w1, cab_w2, ipT, xpT, wT1, wT2);
    hipLaunchKernelGGL(k_inproj,  dim3(768), dim3(256),       0, stream, xn, ipT, xcm, zbuf);
    hipLaunchKernelGGL(k_dwconv,  GRID(DINc * LL),            0, stream, xcm, conv_w, conv_b, xs);
    hipLaunchKernelGGL(k_perm,    GRID(7 * DINc * LL),        0, stream, xs);
    hipLaunchKernelGGL(k_xdbl,    dim3(256), dim3(256),       0, stream, xs, xpT, dtraw, Bb, Cb);
    hipLaunchKernelGGL(k_scan1,   GRID(KK * DINc * NCH * NN), 0, stream, xs, dtraw, Bb, A_logs, dt_w, dt_b, Ap, Bc);
    hipLaunchKernelGGL(k_scan2,   GRID(KK * DINc * NN),       0, stream, Ap, Bc, hst);
    hipLaunchKernelGGL(k_scan3,   GRID(KK * DINc * NCH * NN), 0, stream, xs, dtraw, Bb, Cb, A_logs, dt_w, dt_b, Ds, hst);
    hipLaunchKernelGGL(k_combine, GRID(LL * DINc),            0, stream, xs, acc);
    hipLaunchKernelGGL(k_outnorm, GRID(LL),                   0, stream, acc, zbuf, onw, onb, ybuf);
    hipLaunchKernelGGL(k_outproj, GRID(LL * CC),              0, stream, ybuf, opw, inp, skip1, xafter);
    hipLaunchKernelGGL(k_ln2,     GRID(LL),                   0, stream, xafter, ln2_w, ln2_b, y2);
    hipLaunchKernelGGL(k_conv1,   dim3(512), dim3(256),       0, stream, y2, wT1, part1);
    hipLaunchKernelGGL(k_gelusum, GRID(32 * LL),              0, stream, part1, cab_b1, t1);
    hipLaunchKernelGGL(k_conv2,   dim3(768), dim3(256),       0, stream, t1, wT2, part2);
    hipLaunchKernelGGL(k_conv2sum,GRID(96 * LL),              0, stream, part2, cab_b2, t2);
    hipLaunchKernelGGL(k_mean,    dim3(96), dim3(256),        0, stream, t2, mv);
    hipLaunchKernelGGL(k_mlp,     dim3(1), dim3(128),         0, stream, mv, ca_w1, ca_b1, ca_w2, ca_b2, mv + 96);
    hipLaunchKernelGGL(k_final,   GRID(LL * CC),              0, stream, xafter, skip2, t2, mv + 96, out);
    #undef GRID
}

// Round 9
// 365.018 us; speedup vs baseline: 1.3120x; 1.0840x over previous
//
#include <hip/hip_runtime.h>
#include <math.h>

#define LL 8192
#define CC 96
#define DINc 96
#define NN 16
#define RR 6
#define KK 8
#define Dd 16
#define Hh 16
#define Ww 32
#define NCH 64
#define CHL 128   // LL / NCH

__constant__ int Pc_[4][3] = {{0,1,2},{1,2,0},{2,0,1},{2,1,0}};

__device__ __forceinline__ float silu_(float x){ return x / (1.f + __expf(-x)); }

// ---------------- K1: LN over C at each l -> xn CHANNEL-MAJOR [c][l] ----------------
__global__ void k_ln1(const float* __restrict__ inp, const float* __restrict__ w,
                      const float* __restrict__ b, float* __restrict__ xn_cm) {
    int l = blockIdx.x * blockDim.x + threadIdx.x;
    if (l >= LL) return;
    const float* p = inp + l * CC;
    float m = 0.f;
    for (int c = 0; c < CC; ++c) m += p[c];
    m *= (1.f / CC);
    float v = 0.f;
    for (int c = 0; c < CC; ++c) { float d = p[c] - m; v += d * d; }
    v *= (1.f / CC);
    float r = rsqrtf(v + 1e-6f);
    for (int c = 0; c < CC; ++c) xn_cm[c * LL + l] = (p[c] - m) * r * w[c] + b[c];
}

// ---------------- KW: transpose weights ----------------
__global__ void k_wtrans(const float* __restrict__ inpj, const float* __restrict__ xpw,
                         const float* __restrict__ w1, const float* __restrict__ w2,
                         float* __restrict__ ipT, float* __restrict__ xpT,
                         float* __restrict__ wT1, float* __restrict__ wT2) {
    int idx = blockIdx.x * blockDim.x + threadIdx.x;
    if (idx < 82944) {   // wT1: [ic][tap][oc=32]
        int oc = idx & 31; int tap = (idx >> 5) % 27; int ic = idx / (32 * 27);
        wT1[idx] = w1[(oc * 96 + ic) * 27 + tap];
    }
    if (idx < 82944) {   // wT2: [ic][tap][oc=96]
        int oc = idx % 96; int tap = (idx / 96) % 27; int ic = idx / (96 * 27);
        wT2[idx] = w2[(oc * 32 + ic) * 27 + tap];
    }
    if (idx < 18432) {   // ipT: [c][e=192]
        int e = idx % 192; int c = idx / 192;
        ipT[idx] = inpj[e * 96 + c];
    }
    if (idx < 29184) {   // xpT: [k][c][e=38]
        int e = idx % 38; int c = (idx / 38) % 96; int k = idx / (38 * 96);
        xpT[idx] = xpw[(k * 38 + e) * 96 + c];
    }
}

// ---------------- K2: in_proj; x -> channel-major, z -> ROW-major ----------------
__global__ void k_inproj(const float* __restrict__ xn_cm, const float* __restrict__ ipT,
                         float* __restrict__ xcm, float* __restrict__ z_rm) {
    int bx = blockIdx.x;
    int eb = bx >> 5;                       // 0..23 (uniform)
    int l  = ((bx & 31) << 8) + threadIdx.x;
    int e0 = eb << 3;
    float a[8];
    #pragma unroll
    for (int j = 0; j < 8; ++j) a[j] = 0.f;
    const float* wp = ipT + e0;
    for (int c = 0; c < CC; ++c) {
        float x = xn_cm[c * LL + l];
        const float4* wv = (const float4*)(wp + c * 192);
        float4 wa = wv[0], wb = wv[1];
        a[0] += x * wa.x; a[1] += x * wa.y; a[2] += x * wa.z; a[3] += x * wa.w;
        a[4] += x * wb.x; a[5] += x * wb.y; a[6] += x * wb.z; a[7] += x * wb.w;
    }
    if (e0 < DINc) {
        float* dst = xcm + (long)e0 * LL;
        #pragma unroll
        for (int j = 0; j < 8; ++j) dst[(long)j * LL + l] = a[j];
    } else {
        float* dst = z_rm + (long)l * DINc + (e0 - DINc);
        #pragma unroll
        for (int j = 0; j < 8; ++j) dst[j] = a[j];
    }
}

// ---------------- K3: depthwise conv3d + SiLU -> xs[0] ----------------
__global__ void k_dwconv(const float* __restrict__ xcm, const float* __restrict__ cw,
                         const float* __restrict__ cb, float* __restrict__ xs0) {
    int idx = blockIdx.x * blockDim.x + threadIdx.x;
    if (idx >= DINc * LL) return;
    int l = idx & (LL - 1);
    int c = idx >> 13;
    int w = l & (Ww - 1);
    int h = (l >> 5) & (Hh - 1);
    int d = l >> 9;
    float s = cb[c];
    const float* xp = xcm + c * LL;
    const float* wp = cw + c * 27;
    for (int kd = -1; kd <= 1; ++kd) {
        int dd = d + kd; if ((unsigned)dd >= Dd) continue;
        for (int kh = -1; kh <= 1; ++kh) {
            int hh = h + kh; if ((unsigned)hh >= Hh) continue;
            for (int kw = -1; kw <= 1; ++kw) {
                int ww2 = w + kw; if ((unsigned)ww2 >= Ww) continue;
                s += xp[(dd * Hh + hh) * Ww + ww2] * wp[(kd + 1) * 9 + (kh + 1) * 3 + (kw + 1)];
            }
        }
    }
    xs0[c * LL + l] = silu_(s);
}

// ---------------- K4: build xs[1..7] ----------------
__global__ void k_perm(float* __restrict__ xs) {
    int idx = blockIdx.x * blockDim.x + threadIdx.x;
    if (idx >= 7 * DINc * LL) return;
    int l = idx & (LL - 1);
    int c = (idx >> 13) % DINc;
    int k = idx / (DINc * LL) + 1;
    int i  = (k < 4) ? k : (k - 4);
    int lp = (k < 4) ? l : (LL - 1 - l);
    int p0 = Pc_[i][0], p1 = Pc_[i][1], p2 = Pc_[i][2];
    const int sp[3] = {Dd, Hh, Ww};
    int pd1 = sp[p1], pd2 = sp[p2];
    int i2 = lp % pd2;
    int t  = lp / pd2;
    int i1 = t % pd1;
    int i0 = t / pd1;
    int coord[3];
    coord[p0] = i0; coord[p1] = i1; coord[p2] = i2;
    int o = (coord[0] * Hh + coord[1]) * Ww + coord[2];
    xs[(k * DINc + c) * LL + l] = xs[c * LL + o];
}

// ---------------- K5: x_dbl; dtr [k][l][6]; B/C [k][l/4][n][4] ----------------
__global__ void k_xdbl(const float* __restrict__ xs, const float* __restrict__ xpT,
                       float* __restrict__ dtr, float* __restrict__ Bb, float* __restrict__ Cb) {
    int bx = blockIdx.x;
    int k = bx >> 5;                        // uniform
    int l = ((bx & 31) << 8) + threadIdx.x;
    float acc[38];
    #pragma unroll
    for (int e = 0; e < 38; ++e) acc[e] = 0.f;
    const float* xb = xs + (long)k * DINc * LL + l;
    const float* wb = xpT + k * DINc * 38;
    for (int c = 0; c < DINc; ++c) {
        float x = xb[(long)c * LL];
        const float* wr = wb + c * 38;
        #pragma unroll
        for (int e = 0; e < 38; ++e) acc[e] += x * wr[e];
    }
    float* dtp = dtr + ((long)k * LL + l) * 6;
    #pragma unroll
    for (int r = 0; r < RR; ++r) dtp[r] = acc[r];
    int lq = l >> 2, q = l & 3;
    float* Bp = Bb + (((long)k * 2048 + lq) * 16) * 4 + q;
    float* Cp = Cb + (((long)k * 2048 + lq) * 16) * 4 + q;
    #pragma unroll
    for (int n = 0; n < NN; ++n) { Bp[n * 4] = acc[RR + n]; Cp[n * 4] = acc[RR + NN + n]; }
}

// ---------------- softplus ----------------
__device__ __forceinline__ float softplus_(float x) {
    return (x > 20.f) ? x : __logf(1.f + __expf(x));
}

// ---------------- K7a: chunk-local scan -> (Aprod, Bacc) ----------------
__global__ void k_scan1(const float* __restrict__ xs, const float* __restrict__ dtr,
                        const float* __restrict__ Bb, const float* __restrict__ A_logs,
                        const float* __restrict__ dt_w, const float* __restrict__ dt_b,
                        float* __restrict__ Ap, float* __restrict__ Bc) {
    __shared__ float2 sdu[256];
    int t = blockIdx.x * blockDim.x + threadIdx.x;
    int n = t & 15;
    int gc = t >> 4;
    if (gc >= KK * DINc * NCH) return;
    int gbase = threadIdx.x & ~15;
    int grp = gc >> 6;
    int chunk = gc & (NCH - 1);
    int k = grp / DINc;
    float A_n = -__expf(A_logs[grp * NN + n]);
    float w0 = dt_w[grp * RR + 0], w1 = dt_w[grp * RR + 1], w2 = dt_w[grp * RR + 2];
    float w3 = dt_w[grp * RR + 3], w4 = dt_w[grp * RR + 4], w5 = dt_w[grp * RR + 5];
    float dtb = dt_b[grp];
    const float* drb  = dtr + ((long)k * LL + chunk * CHL) * 6;
    const float* urow = xs + (long)grp * LL + chunk * CHL;
    const float4* B4  = (const float4*)Bb + ((long)k * 2048 + chunk * (CHL / 4)) * 16 + n;
    float hc = 0.f, dsuml = 0.f;
    for (int base = 0; base < CHL; base += 16) {
        int lm = base + n;
        const float2* dp = (const float2*)(drb + lm * 6);
        float2 d0 = dp[0], d1 = dp[1], d2 = dp[2];
        float dtl = dtb + d0.x * w0 + d0.y * w1 + d1.x * w2 + d1.y * w3 + d2.x * w4 + d2.y * w5;
        float dt_lane = softplus_(dtl);
        float u_lane  = urow[lm];
        sdu[threadIdx.x] = make_float2(dt_lane, dt_lane * u_lane);
        dsuml += dt_lane;
        #pragma unroll
        for (int q4 = 0; q4 < 4; ++q4) {
            float4 Bv = B4[((base >> 2) + q4) * 16];
            #pragma unroll
            for (int jj = 0; jj < 4; ++jj) {
                float2 v = sdu[gbase + q4 * 4 + jj];
                float a  = __expf(v.x * A_n);
                float bj = (jj == 0) ? Bv.x : (jj == 1) ? Bv.y : (jj == 2) ? Bv.z : Bv.w;
                hc = a * hc + v.y * bj;
            }
        }
    }
    dsuml += __shfl_xor(dsuml, 1, 16);
    dsuml += __shfl_xor(dsuml, 2, 16);
    dsuml += __shfl_xor(dsuml, 4, 16);
    dsuml += __shfl_xor(dsuml, 8, 16);
    int o = (grp * NN + n) * NCH + chunk;
    Ap[o] = __expf(A_n * dsuml);
    Bc[o] = hc;
}

// ---------------- K7b: combine chunk transfers ----------------
__global__ void k_scan2(const float* __restrict__ Ap, const float* __restrict__ Bc,
                        float* __restrict__ hs) {
    int t = blockIdx.x * blockDim.x + threadIdx.x;
    if (t >= KK * DINc * NN) return;
    int base = t * NCH;
    float h = 0.f;
    for (int c = 0; c < NCH; ++c) {
        hs[base + c] = h;
        h = Ap[base + c] * h + Bc[base + c];
    }
}

// ---------------- K7c: final scan + deferred tree reduce + y write ----------------
__global__ void k_scan3(float* __restrict__ xs_ys, const float* __restrict__ dtr,
                        const float* __restrict__ Bb, const float* __restrict__ Cb,
                        const float* __restrict__ A_logs, const float* __restrict__ dt_w,
                        const float* __restrict__ dt_b, const float* __restrict__ Ds,
                        const float* __restrict__ hs) {
    __shared__ float2 sdu[256];
    int t = blockIdx.x * blockDim.x + threadIdx.x;
    int n = t & 15;
    int gc = t >> 4;
    if (gc >= KK * DINc * NCH) return;
    int gbase = threadIdx.x & ~15;
    int grp = gc >> 6;
    int chunk = gc & (NCH - 1);
    int k = grp / DINc;
    float A_n = -__expf(A_logs[grp * NN + n]);
    float w0 = dt_w[grp * RR + 0], w1 = dt_w[grp * RR + 1], w2 = dt_w[grp * RR + 2];
    float w3 = dt_w[grp * RR + 3], w4 = dt_w[grp * RR + 4], w5 = dt_w[grp * RR + 5];
    float dtb = dt_b[grp];
    float Dv  = Ds[grp];
    const float* drb  = dtr + ((long)k * LL + chunk * CHL) * 6;
    const float4* B4  = (const float4*)Bb + ((long)k * 2048 + chunk * (CHL / 4)) * 16 + n;
    const float4* C4  = (const float4*)Cb + ((long)k * 2048 + chunk * (CHL / 4)) * 16 + n;
    float* urow = xs_ys + (long)grp * LL + chunk * CHL;
    float hc = hs[(grp * NN + n) * NCH + chunk];
    bool b0 = (n & 1), b1 = ((n >> 1) & 1), b2 = ((n >> 2) & 1), b3 = (n >> 3);
    for (int base = 0; base < CHL; base += 16) {
        int lm = base + n;
        const float2* dp = (const float2*)(drb + lm * 6);
        float2 d0 = dp[0], d1 = dp[1], d2 = dp[2];
        float dtl = dtb + d0.x * w0 + d0.y * w1 + d1.x * w2 + d1.y * w3 + d2.x * w4 + d2.y * w5;
        float dt_lane = softplus_(dtl);
        float u_lane  = urow[lm];
        sdu[threadIdx.x] = make_float2(dt_lane, dt_lane * u_lane);
        float p[16];
        #pragma unroll
        for (int q4 = 0; q4 < 4; ++q4) {
            float4 Bv = B4[((base >> 2) + q4) * 16];
            float4 Cv = C4[((base >> 2) + q4) * 16];
            #pragma unroll
            for (int jj = 0; jj < 4; ++jj) {
                int j = q4 * 4 + jj;
                float2 v = sdu[gbase + j];
                float a  = __expf(v.x * A_n);
                float bj = (jj == 0) ? Bv.x : (jj == 1) ? Bv.y : (jj == 2) ? Bv.z : Bv.w;
                float cj = (jj == 0) ? Cv.x : (jj == 1) ? Cv.y : (jj == 2) ? Cv.z : Cv.w;
                hc = a * hc + v.y * bj;
                p[j] = hc * cj;
            }
        }
        float q[8];
        #pragma unroll
        for (int m = 0; m < 8; ++m) {
            float s = b0 ? p[2*m] : p[2*m+1];
            float r = __shfl_xor(s, 1, 16);
            q[m] = (b0 ? p[2*m+1] : p[2*m]) + r;
        }
        float r4[4];
        #pragma unroll
        for (int m = 0; m < 4; ++m) {
            float s = b1 ? q[2*m] : q[2*m+1];
            float r = __shfl_xor(s, 2, 16);
            r4[m] = (b1 ? q[2*m+1] : q[2*m]) + r;
        }
        float t2r[2];
        #pragma unroll
        for (int m = 0; m < 2; ++m) {
            float s = b2 ? r4[2*m] : r4[2*m+1];
            float r = __shfl_xor(s, 4, 16);
            t2r[m] = (b2 ? r4[2*m+1] : r4[2*m]) + r;
        }
        float s = b3 ? t2r[0] : t2r[1];
        float r = __shfl_xor(s, 8, 16);
        float yv = (b3 ? t2r[1] : t2r[0]) + r;
        urow[base + n] = yv + Dv * u_lane;
    }
}

// ---------------- K8+K9 fused: gather-sum 8 dirs + LN + silu(z); wave per l ----------------
__global__ void k_combnorm(const float* __restrict__ ys, const float* __restrict__ z_rm,
                           const float* __restrict__ w, const float* __restrict__ b,
                           float* __restrict__ y) {
    int wave = threadIdx.x >> 6;
    int lane = threadIdx.x & 63;
    int l = blockIdx.x * 4 + wave;
    int d = l >> 9, h = (l >> 5) & 15, wd = l & 31;
    int lps[4];
    lps[0] = l;
    lps[1] = (h * 32 + wd) * 16 + d;
    lps[2] = (wd * 16 + d) * 16 + h;
    lps[3] = (wd * 16 + h) * 16 + d;
    int c0 = lane, c1 = 64 + lane;
    float a0 = 0.f, a1 = 0.f;
    #pragma unroll
    for (int i = 0; i < 4; ++i) {
        a0 += ys[((long)(i * 96) + c0) * LL + lps[i]];
        a0 += ys[((long)((4 + i) * 96) + c0) * LL + (LL - 1 - lps[i])];
    }
    if (lane < 32) {
        #pragma unroll
        for (int i = 0; i < 4; ++i) {
            a1 += ys[((long)(i * 96) + c1) * LL + lps[i]];
            a1 += ys[((long)((4 + i) * 96) + c1) * LL + (LL - 1 - lps[i])];
        }
    }
    float s = a0 + a1;
    #pragma unroll
    for (int o = 1; o < 64; o <<= 1) s += __shfl_xor(s, o, 64);
    float m = s * (1.f / 96.f);
    float d0 = a0 - m;
    float d1 = (lane < 32) ? (a1 - m) : 0.f;
    float ss = d0 * d0 + d1 * d1;
    #pragma unroll
    for (int o = 1; o < 64; o <<= 1) ss += __shfl_xor(ss, o, 64);
    float r = rsqrtf(ss * (1.f / 96.f) + 1e-5f);
    float zz = z_rm[(long)l * 96 + c0];
    y[(long)l * 96 + c0] = (d0 * r * w[c0] + b[c0]) * silu_(zz);
    if (lane < 32) {
        float z1 = z_rm[(long)l * 96 + c1];
        y[(long)l * 96 + c1] = (d1 * r * w[c1] + b[c1]) * silu_(z1);
    }
}

// ---------------- K10: out_proj + skip1 ----------------
__global__ void k_outproj(const float* __restrict__ y, const float* __restrict__ opw,
                          const float* __restrict__ inp, const float* __restrict__ skip1,
                          float* __restrict__ xafter) {
    int idx = blockIdx.x * blockDim.x + threadIdx.x;
    if (idx >= LL * CC) return;
    int c = idx % CC;
    int l = idx / CC;
    const float* yr = y + l * DINc;
    const float* wr = opw + c * DINc;
    float s = 0.f;
    for (int e = 0; e < DINc; ++e) s += yr[e] * wr[e];
    xafter[l * CC + c] = inp[l * CC + c] * skip1[c] + s;
}

// ---------------- K11: LN2 -> channel-major ----------------
__global__ void k_ln2(const float* __restrict__ xafter, const float* __restrict__ w,
                      const float* __restrict__ b, float* __restrict__ y2) {
    int l = blockIdx.x * blockDim.x + threadIdx.x;
    if (l >= LL) return;
    const float* p = xafter + l * CC;
    float m = 0.f;
    for (int c = 0; c < CC; ++c) m += p[c];
    m *= (1.f / CC);
    float v = 0.f;
    for (int c = 0; c < CC; ++c) { float d = p[c] - m; v += d * d; }
    v *= (1.f / CC);
    float r = rsqrtf(v + 1e-5f);
    for (int c = 0; c < CC; ++c) y2[c * LL + l] = (p[c] - m) * r * w[c] + b[c];
}

// ---------------- K12: conv3d 96->32, 4-wide w-vectorized, 16-way ic-split ----------------
__global__ void k_conv1(const float* __restrict__ y2, const float* __restrict__ wT,
                        float* __restrict__ part) {
    int bx = blockIdx.x;
    int g  = bx >> 3;
    int ocg = g & 3;
    int isp = g >> 2;
    int l4 = ((bx & 7) << 8) + threadIdx.x;
    int w0 = (l4 & 7) << 2;
    int h  = (l4 >> 3) & 15;
    int d  = l4 >> 7;
    int l  = (d * Hh + h) * Ww + w0;
    float rmask[9]; int roff[9];
    #pragma unroll
    for (int kd = 0; kd < 3; ++kd) {
        int dd = d + kd - 1;
        bool vd = (unsigned)dd < Dd; int dc = vd ? dd : 0;
        #pragma unroll
        for (int kh = 0; kh < 3; ++kh) {
            int hh = h + kh - 1;
            bool vh = (unsigned)hh < Hh; int hcl = vh ? hh : 0;
            rmask[kd * 3 + kh] = (vd && vh) ? 1.f : 0.f;
            roff[kd * 3 + kh]  = (dc * Hh + hcl) * Ww + w0;
        }
    }
    float mleft  = (w0 > 0)  ? 1.f : 0.f;
    float mright = (w0 < 28) ? 1.f : 0.f;
    float acc[32];
    #pragma unroll
    for (int j = 0; j < 32; ++j) acc[j] = 0.f;
    for (int ic = isp * 6; ic < isp * 6 + 6; ++ic) {
        const float* xp = y2 + (long)ic * LL;
        const float* wb = wT + ic * 864 + ocg * 8;
        #pragma unroll
        for (int r = 0; r < 9; ++r) {
            float rm = rmask[r];
            const float* xr = xp + roff[r];
            float4 xc = *(const float4*)xr;
            float v[6];
            v[0] = xr[-1] * (rm * mleft);
            v[1] = xc.x * rm; v[2] = xc.y * rm; v[3] = xc.z * rm; v[4] = xc.w * rm;
            v[5] = xr[4] * (rm * mright);
            #pragma unroll
            for (int t = 0; t < 3; ++t) {
                const float4* wv = (const float4*)(wb + (r * 3 + t) * 32);
                float4 wa = wv[0], wbv = wv[1];
                #pragma unroll
                for (int p = 0; p < 4; ++p) {
                    float x = v[t + p];
                    acc[0  + p] += x * wa.x;  acc[4  + p] += x * wa.y;
                    acc[8  + p] += x * wa.z;  acc[12 + p] += x * wa.w;
                    acc[16 + p] += x * wbv.x; acc[20 + p] += x * wbv.y;
                    acc[24 + p] += x * wbv.z; acc[28 + p] += x * wbv.w;
                }
            }
        }
    }
    float* pp = part + ((long)(isp * 32 + ocg * 8)) * LL + l;
    #pragma unroll
    for (int oc = 0; oc < 8; ++oc)
        *(float4*)(pp + (long)oc * LL) = make_float4(acc[oc*4+0], acc[oc*4+1], acc[oc*4+2], acc[oc*4+3]);
}

// ---------------- K12b: t1 = GELU(sum 16 partials + bias) ----------------
__global__ void k_gelusum(const float* __restrict__ part, const float* __restrict__ b1,
                          float* __restrict__ t1) {
    int idx = blockIdx.x * blockDim.x + threadIdx.x;
    if (idx >= 32 * LL) return;
    int l = idx & (LL - 1);
    int oc = idx >> 13;
    float s = b1[oc];
    #pragma unroll
    for (int isp = 0; isp < 16; ++isp)
        s += part[((long)(isp * 32 + oc)) * LL + l];
    t1[oc * LL + l] = 0.5f * s * (1.f + erff(s * 0.70710678118654752f));
}

// ---------------- K13: conv3d 32->96, 4-wide w-vectorized, 8-way ic-split ----------------
__global__ void k_conv2(const float* __restrict__ t1, const float* __restrict__ wT,
                        float* __restrict__ part) {
    int bx = blockIdx.x;
    int g  = bx >> 3;
    int ocg = g % 12;
    int isp = g / 12;
    int l4 = ((bx & 7) << 8) + threadIdx.x;
    int w0 = (l4 & 7) << 2;
    int h  = (l4 >> 3) & 15;
    int d  = l4 >> 7;
    int l  = (d * Hh + h) * Ww + w0;
    float rmask[9]; int roff[9];
    #pragma unroll
    for (int kd = 0; kd < 3; ++kd) {
        int dd = d + kd - 1;
        bool vd = (unsigned)dd < Dd; int dc = vd ? dd : 0;
        #pragma unroll
        for (int kh = 0; kh < 3; ++kh) {
            int hh = h + kh - 1;
            bool vh = (unsigned)hh < Hh; int hcl = vh ? hh : 0;
            rmask[kd * 3 + kh] = (vd && vh) ? 1.f : 0.f;
            roff[kd * 3 + kh]  = (dc * Hh + hcl) * Ww + w0;
        }
    }
    float mleft  = (w0 > 0)  ? 1.f : 0.f;
    float mright = (w0 < 28) ? 1.f : 0.f;
    float acc[32];
    #pragma unroll
    for (int j = 0; j < 32; ++j) acc[j] = 0.f;
    for (int ic = isp * 4; ic < isp * 4 + 4; ++ic) {
        const float* xp = t1 + (long)ic * LL;
        const float* wb = wT + ic * 2592 + ocg * 8;
        #pragma unroll
        for (int r = 0; r < 9; ++r) {
            float rm = rmask[r];
            const float* xr = xp + roff[r];
            float4 xc = *(const float4*)xr;
            float v[6];
            v[0] = xr[-1] * (rm * mleft);
            v[1] = xc.x * rm; v[2] = xc.y * rm; v[3] = xc.z * rm; v[4] = xc.w * rm;
            v[5] = xr[4] * (rm * mright);
            #pragma unroll
            for (int t = 0; t < 3; ++t) {
                const float4* wv = (const float4*)(wb + (r * 3 + t) * 96);
                float4 wa = wv[0], wbv = wv[1];
                #pragma unroll
                for (int p = 0; p < 4; ++p) {
                    float x = v[t + p];
                    acc[0  + p] += x * wa.x;  acc[4  + p] += x * wa.y;
                    acc[8  + p] += x * wa.z;  acc[12 + p] += x * wa.w;
                    acc[16 + p] += x * wbv.x; acc[20 + p] += x * wbv.y;
                    acc[24 + p] += x * wbv.z; acc[28 + p] += x * wbv.w;
                }
            }
        }
    }
    float* pp = part + ((long)(isp * 96 + ocg * 8)) * LL + l;
    #pragma unroll
    for (int oc = 0; oc < 8; ++oc)
        *(float4*)(pp + (long)oc * LL) = make_float4(acc[oc*4+0], acc[oc*4+1], acc[oc*4+2], acc[oc*4+3]);
}

// ---------------- K13b: t2 = sum 8 partials + bias ----------------
__global__ void k_conv2sum(const float* __restrict__ part, const float* __restrict__ b2,
                           float* __restrict__ t2) {
    int idx = blockIdx.x * blockDim.x + threadIdx.x;
    if (idx >= 96 * LL) return;
    int l = idx & (LL - 1);
    int oc = idx >> 13;
    float s = b2[oc];
    #pragma unroll
    for (int isp = 0; isp < 8; ++isp)
        s += part[((long)(isp * 96 + oc)) * LL + l];
    t2[oc * LL + l] = s;
}

// ---------------- K14a: per-channel mean ----------------
__global__ void k_mean(const float* __restrict__ t2, float* __restrict__ mbuf) {
    __shared__ float sm[256];
    int c = blockIdx.x;
    float a = 0.f;
    for (int l = threadIdx.x; l < LL; l += 256) a += t2[c * LL + l];
    sm[threadIdx.x] = a;
    __syncthreads();
    for (int o = 128; o > 0; o >>= 1) {
        if (threadIdx.x < o) sm[threadIdx.x] += sm[threadIdx.x + o];
        __syncthreads();
    }
    if (threadIdx.x == 0) mbuf[c] = sm[0] * (1.f / LL);
}

// ---------------- K14b: channel-attention MLP ----------------
__global__ void k_mlp(const float* __restrict__ mbuf, const float* __restrict__ w1,
                      const float* __restrict__ b1, const float* __restrict__ w2,
                      const float* __restrict__ b2, float* __restrict__ v2) {
    __shared__ float v[48];
    int t = threadIdx.x;
    if (t < 48) {
        float s = b1[t];
        for (int c = 0; c < 96; ++c) s += mbuf[c] * w1[t * 96 + c];
        v[t] = fmaxf(s, 0.f);
    }
    __syncthreads();
    if (t < 96) {
        float s = b2[t];
        for (int j = 0; j < 48; ++j) s += v[j] * w2[t * 48 + j];
        v2[t] = 1.f / (1.f + __expf(-s));
    }
}

// ---------------- K15: final residual ----------------
__global__ void k_final(const float* __restrict__ xafter, const float* __restrict__ skip2,
                        const float* __restrict__ t2, const float* __restrict__ v2,
                        float* __restrict__ out) {
    int idx = blockIdx.x * blockDim.x + threadIdx.x;
    if (idx >= LL * CC) return;
    int c = idx % CC;
    int l = idx / CC;
    out[l * CC + c] = xafter[l * CC + c] * skip2[c] + t2[c * LL + l] * v2[c];
}

// ---------------- workspace layout (float offsets) ----------------
static const size_t OFF_XS     = 0;          // 8*96*8192 (xs -> ys; conv partials after combnorm)
static const size_t OFF_Z      = 6291456;    // 786432 (z row-major)
static const size_t OFF_XCM    = 7077888;    // 786432
static const size_t OFF_XN     = 7864320;    // 786432 (xn_cm; reused as y)
static const size_t OFF_DTRAW  = 8650752;    // 393216 ([k][l][6])
static const size_t OFF_BB     = 9043968;    // 1048576 ([k][l/4][n][4])
static const size_t OFF_CB     = 10092544;   // 1048576
static const size_t OFF_XAFTER = 11141120;   // 786432 (scan: Ap)
static const size_t OFF_Y2     = 11927552;   // 786432 (scan: Bc)
static const size_t OFF_T1     = 12713984;   // 262144
static const size_t OFF_T2     = 12976128;   // 786432 (scan: hs)
static const size_t OFF_MV     = 13762560;   // 256
static const size_t OFF_WT1    = 13762816;   // 82944
static const size_t OFF_WT2    = 13845760;   // 82944
static const size_t OFF_IPT    = 13928704;   // 18432
static const size_t OFF_XPT    = 13947136;   // 29184

extern "C" void kernel_launch(void* const* d_in, const int* in_sizes, int n_in,
                              void* d_out, int out_size, void* d_ws, size_t ws_size,
                              hipStream_t stream) {
    const float* inp    = (const float*)d_in[0];
    const float* ln1_w  = (const float*)d_in[2];
    const float* ln1_b  = (const float*)d_in[3];
    const float* skip1  = (const float*)d_in[4];
    const float* skip2  = (const float*)d_in[5];
    const float* ln2_w  = (const float*)d_in[6];
    const float* ln2_b  = (const float*)d_in[7];
    const float* inpj   = (const float*)d_in[8];
    const float* conv_w = (const float*)d_in[9];
    const float* conv_b = (const float*)d_in[10];
    const float* xpw    = (const float*)d_in[11];
    const float* dt_w   = (const float*)d_in[12];
    const float* dt_b   = (const float*)d_in[13];
    const float* A_logs = (const float*)d_in[14];
    const float* Ds     = (const float*)d_in[15];
    const float* onw    = (const float*)d_in[16];
    const float* onb    = (const float*)d_in[17];
    const float* opw    = (const float*)d_in[18];
    const float* cab_w1 = (const float*)d_in[19];
    const float* cab_b1 = (const float*)d_in[20];
    const float* cab_w2 = (const float*)d_in[21];
    const float* cab_b2 = (const float*)d_in[22];
    const float* ca_w1  = (const float*)d_in[23];
    const float* ca_b1  = (const float*)d_in[24];
    const float* ca_w2  = (const float*)d_in[25];
    const float* ca_b2  = (const float*)d_in[26];

    float* ws = (float*)d_ws;
    float* xs     = ws + OFF_XS;
    float* zbuf   = ws + OFF_Z;
    float* xcm    = ws + OFF_XCM;
    float* xn     = ws + OFF_XN;
    float* dtr    = ws + OFF_DTRAW;
    float* Bb     = ws + OFF_BB;
    float* Cb     = ws + OFF_CB;
    float* xafter = ws + OFF_XAFTER;
    float* y2     = ws + OFF_Y2;
    float* t1     = ws + OFF_T1;
    float* t2     = ws + OFF_T2;
    float* mv     = ws + OFF_MV;
    float* wT1    = ws + OFF_WT1;
    float* wT2    = ws + OFF_WT2;
    float* ipT    = ws + OFF_IPT;
    float* xpT    = ws + OFF_XPT;
    float* ybuf   = xn;                  // reuse (xn dead after inproj)
    float* Ap     = xafter;              // 786432 == 8*96*16*64 exact
    float* Bc     = y2;
    float* hst    = t2;
    float* part1  = xs;                  // xs dead after combnorm
    float* part2  = xs;

    float* out = (float*)d_out;
    #define GRID(n) dim3((unsigned)(((n) + 255) / 256)), dim3(256)

    hipLaunchKernelGGL(k_ln1,     GRID(LL),                   0, stream, inp, ln1_w, ln1_b, xn);
    hipLaunchKernelGGL(k_wtrans,  GRID(82944),                0, stream, inpj, xpw, cab_w1, cab_w2, ipT, xpT, wT1, wT2);
    hipLaunchKernelGGL(k_inproj,  dim3(768), dim3(256),       0, stream, xn, ipT, xcm, zbuf);
    hipLaunchKernelGGL(k_dwconv,  GRID(DINc * LL),            0, stream, xcm, conv_w, conv_b, xs);
    hipLaunchKernelGGL(k_perm,    GRID(7 * DINc * LL),        0, stream, xs);
    hipLaunchKernelGGL(k_xdbl,    dim3(256), dim3(256),       0, stream, xs, xpT, dtr, Bb, Cb);
    hipLaunchKernelGGL(k_scan1,   GRID(KK * DINc * NCH * NN), 0, stream, xs, dtr, Bb, A_logs, dt_w, dt_b, Ap, Bc);
    hipLaunchKernelGGL(k_scan2,   GRID(KK * DINc * NN),       0, stream, Ap, Bc, hst);
    hipLaunchKernelGGL(k_scan3,   GRID(KK * DINc * NCH * NN), 0, stream, xs, dtr, Bb, Cb, A_logs, dt_w, dt_b, Ds, hst);
    hipLaunchKernelGGL(k_combnorm,dim3(LL / 4), dim3(256),    0, stream, xs, zbuf, onw, onb, ybuf);
    hipLaunchKernelGGL(k_outproj, GRID(LL * CC),              0, stream, ybuf, opw, inp, skip1, xafter);
    hipLaunchKernelGGL(k_ln2,     GRID(LL),                   0, stream, xafter, ln2_w, ln2_b, y2);
    hipLaunchKernelGGL(k_conv1,   dim3(512), dim3(256),       0, stream, y2, wT1, part1);
    hipLaunchKernelGGL(k_gelusum, GRID(32 * LL),              0, stream, part1, cab_b1, t1);
    hipLaunchKernelGGL(k_conv2,   dim3(768), dim3(256),       0, stream, t1, wT2, part2);
    hipLaunchKernelGGL(k_conv2sum,GRID(96 * LL),              0, stream, part2, cab_b2, t2);
    hipLaunchKernelGGL(k_mean,    dim3(96), dim3(256),        0, stream, t2, mv);
    hipLaunchKernelGGL(k_mlp,     dim3(1), dim3(128),         0, stream, mv, ca_w1, ca_b1, ca_w2, ca_b2, mv + 96);
    hipLaunchKernelGGL(k_final,   GRID(LL * CC),              0, stream, xafter, skip2, t2, mv + 96, out);
    #undef GRID
}